// Round 5
// baseline (705.189 us; speedup 1.0000x reference)
//
#include <hip/hip_runtime.h>
#include <hip/hip_bf16.h>

typedef float fv4 __attribute__((ext_vector_type(4)));
typedef __bf16 bfv8 __attribute__((ext_vector_type(8)));
typedef unsigned short u16;

#define DEV static __device__ __forceinline__

DEV u16 f2bf(float f) {
  union { __hip_bfloat16 h; u16 u; } c;
  c.h = __float2bfloat16(f);
  return c.u;
}

DEV void glds16(const void* g, void* l) {
  __builtin_amdgcn_global_load_lds(
      (const __attribute__((address_space(1))) unsigned int*)g,
      (__attribute__((address_space(3))) unsigned int*)l, 16, 0, 0);
}

DEV fv4 mfma16(bfv8 a, bfv8 b, fv4 c) {
  return __builtin_amdgcn_mfma_f32_16x16x32_bf16(a, b, c, 0, 0, 0);
}

// ---------------------------------------------------------------------------
// GEMM: C[MrxN] = A[Mr x K](bf16, row stride lda) @ Bt[N x K](bf16, stride
// ldb)^T + bias (+resid, relu). 128x128 tile, BK=32, 4 waves, 4x4 frags.
// LDS XOR-swizzle (row&7)<<4 via pre-swizzled global_load_lds source.
// ---------------------------------------------------------------------------
template <bool OUT_BF16, bool RELU, bool RESID, bool BIAS>
__global__ __launch_bounds__(256, 2) void gemm_k(
    const u16* __restrict__ A, const u16* __restrict__ Bt,
    const float* __restrict__ bias, const float* __restrict__ resid,
    void* __restrict__ outp, int K, int N, int lda, int ldb) {
  __shared__ __align__(16) u16 lds[2][2][128 * 32];
  const int tid = threadIdx.x;
  const int lane = tid & 63, wid = tid >> 6;
  const int bm0 = blockIdx.y * 128, bn0 = blockIdx.x * 128;
  const int wr = (wid >> 1) * 64, wc = (wid & 1) * 64;
  const int g = lane >> 4, ml = lane & 15;

  fv4 acc[4][4];
#pragma unroll
  for (int i = 0; i < 4; ++i)
#pragma unroll
    for (int j = 0; j < 4; ++j) acc[i][j] = (fv4)0.f;

  const int nK = K >> 5;

  auto stage = [&](int t) {
    const int buf = t & 1;
    const int k0 = t * 32;
#pragma unroll
    for (int p = 0; p < 2; ++p) {
      const int s = p * 256 + tid;
      const int r0 = ((s >> 2) & 1) ^ ((s >> 4) & 1);
      const int row = ((s >> 3) << 1) | r0;
      const int chunk = (s & 3) ^ (row & 3);
      glds16(A + (size_t)(bm0 + row) * lda + k0 + chunk * 8,
             &lds[buf][0][(p * 256 + wid * 64) * 8]);
      glds16(Bt + (size_t)(bn0 + row) * ldb + k0 + chunk * 8,
             &lds[buf][1][(p * 256 + wid * 64) * 8]);
    }
  };

  stage(0);
  for (int t = 0; t < nK; ++t) {
    __syncthreads();
    if (t + 1 < nK) stage(t + 1);
    const u16* Ab = lds[t & 1][0];
    const u16* Bb = lds[t & 1][1];
    bfv8 af[4], bf[4];
#pragma unroll
    for (int f = 0; f < 4; ++f) {
      const int ra = wr + f * 16 + ml;
      const int ba = ((ra << 6) + (g << 4)) ^ ((ra & 7) << 4);
      af[f] = *(const bfv8*)&Ab[ba >> 1];
      const int rb = wc + f * 16 + ml;
      const int bb = ((rb << 6) + (g << 4)) ^ ((rb & 7) << 4);
      bf[f] = *(const bfv8*)&Bb[bb >> 1];
    }
#pragma unroll
    for (int i = 0; i < 4; ++i)
#pragma unroll
      for (int j = 0; j < 4; ++j) acc[i][j] = mfma16(af[i], bf[j], acc[i][j]);
  }

#pragma unroll
  for (int j = 0; j < 4; ++j) {
    const int n = bn0 + wc + j * 16 + ml;
    float bv = 0.f;
    if (BIAS) bv = bias[n];
#pragma unroll
    for (int i = 0; i < 4; ++i) {
      const int m0r = bm0 + wr + i * 16 + g * 4;
#pragma unroll
      for (int r = 0; r < 4; ++r) {
        float val = acc[i][j][r] + bv;
        if (RESID) val += resid[(size_t)(m0r + r) * N + n];
        if (RELU) val = fmaxf(val, 0.f);
        if (OUT_BF16)
          ((u16*)outp)[(size_t)(m0r + r) * N + n] = f2bf(val);
        else
          ((float*)outp)[(size_t)(m0r + r) * N + n] = val;
      }
    }
  }
}

// ---------------------------------------------------------------------------
// Attention with rank-1 logits (the reference's einsum 'mbhi,nbhj->mnbh'
// sums i and j separately): logits[m,n] = qs[m]*ks[n]; softmax over n;
// pooled = W @ V. Block: one (b,h), 64 m-rows, 4 waves x 16 rows.
// P computed in registers (fp32 logits, exp, ->bf16) feeding PV MFMA.
// ---------------------------------------------------------------------------
__global__ __launch_bounds__(256, 2) void attn2_k(
    const u16* __restrict__ v, const float* __restrict__ qsarr,
    const float* __restrict__ ksarr, const unsigned char* __restrict__ mask,
    u16* __restrict__ pooled) {
  __shared__ float ks_s[1024];
  __shared__ float red[16];
  __shared__ int anym_s;
  __shared__ float zl[4][16];
  __shared__ __align__(16) u16 VT[64 * 72];

  const int tid = threadIdx.x, lane = tid & 63, wid = tid >> 6;
  const int g = lane >> 4, ml = lane & 15;
  const int b = blockIdx.y >> 4, h = blockIdx.y & 15;
  const int m0 = blockIdx.x * 64;

  if (tid == 0) anym_s = 0;
  __syncthreads();

  // stage ks row (fp32) + unmasked max/min + any-mask flag
  const float* ksp = ksarr + (size_t)(b * 16 + h) * 1024;
  float4 kv = *(const float4*)&ksp[tid * 4];
  *(float4*)&ks_s[tid * 4] = kv;
  const float kvv[4] = {kv.x, kv.y, kv.z, kv.w};
  float mx = -3.4e38f, mn = 3.4e38f;
  int am = 0;
#pragma unroll
  for (int j = 0; j < 4; ++j) {
    const int n = tid * 4 + j;
    const int mk = mask[(size_t)n * 8 + b] ? 1 : 0;
    am |= mk;
    if (!mk) { mx = fmaxf(mx, kvv[j]); mn = fminf(mn, kvv[j]); }
  }
  if (am) atomicOr(&anym_s, 1);
#pragma unroll
  for (int s = 1; s <= 32; s <<= 1) {
    mx = fmaxf(mx, __shfl_xor(mx, s, 64));
    mn = fminf(mn, __shfl_xor(mn, s, 64));
  }
  if (lane == 0) { red[wid] = mx; red[8 + wid] = mn; }
  __syncthreads();
  const float smax = fmaxf(fmaxf(red[0], red[1]), fmaxf(red[2], red[3]));
  const float smin = fminf(fminf(red[8], red[9]), fminf(red[10], red[11]));
  const int anym = anym_s;

  // this lane's q-sum scalar (A-row = ml within wave) and row max M
  const float c = qsarr[(size_t)(b * 16 + h) * 1024 + m0 + wid * 16 + ml];
  const float M = (c >= 0.f) ? c * smax : c * smin;  // M >= 0 always

  fv4 o[4];
#pragma unroll
  for (int d = 0; d < 4; ++d) o[d] = (fv4)0.f;
  float zacc = 0.f;

  for (int nt = 0; nt < 16; ++nt) {
    const int n0 = nt * 64;
    if (nt) __syncthreads();  // VT consumed by all waves before overwrite
    // stage V transposed: VT[d][n], padded stride 72
#pragma unroll
    for (int p = 0; p < 2; ++p) {
      const int s = p * 256 + tid;
      const int n = s >> 3, cc = s & 7;
      bfv8 vv = *(const bfv8*)&v[((size_t)(n0 + n) * 8 + b) * 1024 + h * 64 + cc * 8];
      const u16* vb = (const u16*)&vv;
#pragma unroll
      for (int j = 0; j < 8; ++j) VT[(cc * 8 + j) * 72 + n] = vb[j];
    }
    __syncthreads();

    // P fragments in registers: p = exp(c*s - M)
    bfv8 pa[2];
#pragma unroll
    for (int kk = 0; kk < 2; ++kk) {
      const int kb = n0 + kk * 32 + g * 8;
      const float4 s0 = *(const float4*)&ks_s[kb - n0 + n0];  // &ks_s[kb]
      const float4 s1 = *(const float4*)&ks_s[kb + 4];
      const float sv[8] = {s0.x, s0.y, s0.z, s0.w, s1.x, s1.y, s1.z, s1.w};
      u16 tmp[8];
#pragma unroll
      for (int j = 0; j < 8; ++j) {
        float p = __expf(fmaf(c, sv[j], -M));
        if (anym && mask[(size_t)(kb + j) * 8 + b]) p = 0.f;
        zacc += p;
        tmp[j] = f2bf(p);
      }
      pa[kk] = *(const bfv8*)tmp;
    }
#pragma unroll
    for (int kk = 0; kk < 2; ++kk)
#pragma unroll
      for (int ds = 0; ds < 4; ++ds) {
        bfv8 vf = *(const bfv8*)&VT[(ds * 16 + ml) * 72 + kk * 32 + g * 8];
        o[ds] = mfma16(pa[kk], vf, o[ds]);
      }
  }

  // Z per row ml: sum partials across the 4 g-groups
  zacc += __shfl_xor(zacc, 16, 64);
  zacc += __shfl_xor(zacc, 32, 64);
  if (g == 0) zl[wid][ml] = zacc;
  asm volatile("" ::: "memory");  // same-wave LDS write -> read
  float zin[4];
#pragma unroll
  for (int r = 0; r < 4; ++r) zin[r] = 1.f / zl[wid][g * 4 + r];

  __syncthreads();  // all MFMAs done; reuse VT for output staging
  u16* stg = &VT[wid * 16 * 72];
#pragma unroll
  for (int ds = 0; ds < 4; ++ds)
#pragma unroll
    for (int r = 0; r < 4; ++r)
      stg[(g * 4 + r) * 72 + ds * 16 + ml] = f2bf(o[ds][r] * zin[r]);
  asm volatile("" ::: "memory");
#pragma unroll
  for (int p = 0; p < 2; ++p) {
    const int ch = p * 64 + lane;
    const int mr = ch >> 3, cc = ch & 7;
    bfv8 val = *(const bfv8*)&stg[mr * 72 + cc * 8];
    *(bfv8*)&pooled[((size_t)(m0 + wid * 16 + mr) * 8 + b) * 1024 + h * 64 + cc * 8] = val;
  }
}

// ---------------------------------------------------------------------------
// LayerNorm: one block per row of 1024, fp32 in -> bf16 out
// ---------------------------------------------------------------------------
__global__ __launch_bounds__(256) void ln_k(
    const float* __restrict__ x, const float* __restrict__ gw,
    const float* __restrict__ bw, u16* __restrict__ out) {
  __shared__ float sm[8];
  const int row = blockIdx.x, tid = threadIdx.x;
  const int lane = tid & 63, wid = tid >> 6;
  const float4 xv = *(const float4*)&x[(size_t)row * 1024 + tid * 4];
  float s = xv.x + xv.y + xv.z + xv.w;
  float q = xv.x * xv.x + xv.y * xv.y + xv.z * xv.z + xv.w * xv.w;
#pragma unroll
  for (int m = 1; m <= 32; m <<= 1) {
    s += __shfl_xor(s, m, 64);
    q += __shfl_xor(q, m, 64);
  }
  if (lane == 0) { sm[wid] = s; sm[4 + wid] = q; }
  __syncthreads();
  s = sm[0] + sm[1] + sm[2] + sm[3];
  q = sm[4] + sm[5] + sm[6] + sm[7];
  const float mean = s * (1.f / 1024.f);
  const float var = q * (1.f / 1024.f) - mean * mean;
  const float rstd = rsqrtf(var + 1e-5f);
  const float4 gv = *(const float4*)&gw[tid * 4];
  const float4 bv = *(const float4*)&bw[tid * 4];
  ushort4 ov;
  ov.x = f2bf((xv.x - mean) * rstd * gv.x + bv.x);
  ov.y = f2bf((xv.y - mean) * rstd * gv.y + bv.y);
  ov.z = f2bf((xv.z - mean) * rstd * gv.z + bv.z);
  ov.w = f2bf((xv.w - mean) * rstd * gv.w + bv.w);
  *(ushort4*)&out[(size_t)row * 1024 + tid * 4] = ov;
}

// ---------------------------------------------------------------------------
// qks: per row mb, fused fp32 LN + skinny GEMM against summed weights
// wqsa[k][0..15]=q-heads, [16..31]=k-heads. Outputs qsarr/ksarr [b][h][m].
// ---------------------------------------------------------------------------
__global__ __launch_bounds__(256) void qks_k(
    const float* __restrict__ x, const float* __restrict__ gw,
    const float* __restrict__ bw, const float* __restrict__ wqsa,
    const float* __restrict__ bqks, float* __restrict__ qsarr,
    float* __restrict__ ksarr) {
  __shared__ float sm[8];
  __shared__ float wred[4][32];
  const int row = blockIdx.x, tid = threadIdx.x;
  const int lane = tid & 63, wid = tid >> 6;
  const float4 xv = *(const float4*)&x[(size_t)row * 1024 + tid * 4];
  float s = xv.x + xv.y + xv.z + xv.w;
  float q = xv.x * xv.x + xv.y * xv.y + xv.z * xv.z + xv.w * xv.w;
#pragma unroll
  for (int m = 1; m <= 32; m <<= 1) {
    s += __shfl_xor(s, m, 64);
    q += __shfl_xor(q, m, 64);
  }
  if (lane == 0) { sm[wid] = s; sm[4 + wid] = q; }
  __syncthreads();
  s = sm[0] + sm[1] + sm[2] + sm[3];
  q = sm[4] + sm[5] + sm[6] + sm[7];
  const float mean = s * (1.f / 1024.f);
  const float var = q * (1.f / 1024.f) - mean * mean;
  const float rstd = rsqrtf(var + 1e-5f);
  const float4 gv = *(const float4*)&gw[tid * 4];
  const float4 bv = *(const float4*)&bw[tid * 4];
  const float xn[4] = {(xv.x - mean) * rstd * gv.x + bv.x,
                       (xv.y - mean) * rstd * gv.y + bv.y,
                       (xv.z - mean) * rstd * gv.z + bv.z,
                       (xv.w - mean) * rstd * gv.w + bv.w};
  float acc[32];
#pragma unroll
  for (int i = 0; i < 32; ++i) acc[i] = 0.f;
#pragma unroll
  for (int j = 0; j < 4; ++j) {
    const float* wp = wqsa + (size_t)(tid * 4 + j) * 32;
#pragma unroll
    for (int i = 0; i < 32; ++i) acc[i] = fmaf(xn[j], wp[i], acc[i]);
  }
#pragma unroll
  for (int i = 0; i < 32; ++i) {
#pragma unroll
    for (int m = 1; m <= 32; m <<= 1) acc[i] += __shfl_xor(acc[i], m, 64);
  }
  if (lane == 0) {
#pragma unroll
    for (int i = 0; i < 32; ++i) wred[wid][i] = acc[i];
  }
  __syncthreads();
  if (tid < 32) {
    const float tot = wred[0][tid] + wred[1][tid] + wred[2][tid] +
                      wred[3][tid] + bqks[tid];
    const int m = row >> 3, b = row & 7;
    if (tid < 16)
      qsarr[(size_t)(b * 16 + tid) * 1024 + m] = tot;
    else
      ksarr[(size_t)(b * 16 + (tid - 16)) * 1024 + m] = tot;
  }
}

// wqsa[k][h32] = sum over the 64 in-head cols of wq (h32<16) / wk (h32>=16)
__global__ void wsum_k(const float* __restrict__ wq,
                       const float* __restrict__ wk,
                       float* __restrict__ wqsa) {
  const int k = blockIdx.x, t = threadIdx.x;
  const int h32 = t >> 3, ch = t & 7;
  const float* src = (h32 < 16) ? (wq + (size_t)k * 1024 + h32 * 64 + ch * 8)
                                : (wk + (size_t)k * 1024 + (h32 - 16) * 64 + ch * 8);
  float s = 0.f;
#pragma unroll
  for (int j = 0; j < 8; ++j) s += src[j];
  s += __shfl_xor(s, 1, 64);
  s += __shfl_xor(s, 2, 64);
  s += __shfl_xor(s, 4, 64);
  if (ch == 0) wqsa[k * 32 + h32] = s;
}

__global__ void bsum_k(const float* __restrict__ bq,
                       const float* __restrict__ bk,
                       float* __restrict__ bqks) {
  const int t = threadIdx.x;
  if (t < 32) {
    const float* s = (t < 16) ? (bq + t * 64) : (bk + (t - 16) * 64);
    float a = 0.f;
    for (int j = 0; j < 64; ++j) a += s[j];
    bqks[t] = a;
  }
}

// W (RxC fp32) -> Wt (CxR bf16)
__global__ void tr_k(const float* __restrict__ W, u16* __restrict__ Wt,
                     int R, int C) {
  __shared__ float tile[32][33];
  const int x = threadIdx.x, y = threadIdx.y;
  const int c0 = blockIdx.x * 32, r0 = blockIdx.y * 32;
#pragma unroll
  for (int i = 0; i < 4; ++i)
    tile[y + i * 8][x] = W[(size_t)(r0 + y + i * 8) * C + c0 + x];
  __syncthreads();
#pragma unroll
  for (int i = 0; i < 4; ++i)
    Wt[(size_t)(c0 + y + i * 8) * R + r0 + x] = f2bf(tile[x][y + i * 8]);
}

extern "C" void kernel_launch(void* const* d_in, const int* in_sizes, int n_in,
                              void* d_out, int out_size, void* d_ws,
                              size_t ws_size, hipStream_t stream) {
  const float* x = (const float*)d_in[0];
  const unsigned char* mask = (const unsigned char*)d_in[1];
  const float* ln1g = (const float*)d_in[2];
  const float* ln1b = (const float*)d_in[3];
  const float* wq = (const float*)d_in[4];
  const float* bq = (const float*)d_in[5];
  const float* wk = (const float*)d_in[6];
  const float* bk = (const float*)d_in[7];
  const float* wv = (const float*)d_in[8];
  const float* bv = (const float*)d_in[9];
  const float* wo = (const float*)d_in[10];
  const float* bo = (const float*)d_in[11];
  const float* ln2g = (const float*)d_in[12];
  const float* ln2b = (const float*)d_in[13];
  const float* w1 = (const float*)d_in[14];
  const float* b1 = (const float*)d_in[15];
  const float* w2 = (const float*)d_in[16];
  const float* b2 = (const float*)d_in[17];

  // ---- workspace layout (~69 MB) ----
  u16* wvT = (u16*)d_ws;                        // 1024x1024 bf16
  u16* woT = wvT + 1024 * 1024;                 // 1024x1024
  u16* w1T = woT + 1024 * 1024;                 // 4096x1024
  u16* w2T = w1T + 4096 * 1024;                 // 1024x4096
  float* wqsa = (float*)(w2T + 1024 * 4096);    // [1024][32] f32
  float* bqks = wqsa + 1024 * 32;               // 32 f32
  float* qsarr = bqks + 32;                     // [8][16][1024] f32
  float* ksarr = qsarr + 8 * 16 * 1024;         // [8][16][1024] f32
  u16* v = (u16*)(ksarr + 8 * 16 * 1024);       // 8192x1024 bf16
  u16* pooled = v + (size_t)8192 * 1024;        // 8192x1024 bf16
  u16* xn = pooled + (size_t)8192 * 1024;       // 8192x1024 bf16
  u16* hbuf = v;                                // alias: 8192x2048 (v+pooled)
  float* x2 = (float*)d_out;                    // fp32 residual in d_out

  const dim3 b256(256), btr(32, 8);
  tr_k<<<dim3(32, 32), btr, 0, stream>>>(wv, wvT, 1024, 1024);
  tr_k<<<dim3(32, 32), btr, 0, stream>>>(wo, woT, 1024, 1024);
  tr_k<<<dim3(128, 32), btr, 0, stream>>>(w1, w1T, 1024, 4096);
  tr_k<<<dim3(32, 128), btr, 0, stream>>>(w2, w2T, 4096, 1024);
  wsum_k<<<dim3(1024), b256, 0, stream>>>(wq, wk, wqsa);
  bsum_k<<<dim3(1), dim3(64), 0, stream>>>(bq, bk, bqks);

  ln_k<<<dim3(8192), b256, 0, stream>>>(x, ln1g, ln1b, xn);
  qks_k<<<dim3(8192), b256, 0, stream>>>(x, ln1g, ln1b, wqsa, bqks, qsarr,
                                         ksarr);
  gemm_k<true, false, false, true><<<dim3(8, 64), b256, 0, stream>>>(
      xn, wvT, bv, nullptr, v, 1024, 1024, 1024, 1024);
  attn2_k<<<dim3(16, 128), b256, 0, stream>>>(v, qsarr, ksarr, mask, pooled);
  gemm_k<false, false, true, true><<<dim3(8, 64), b256, 0, stream>>>(
      pooled, woT, bo, x, x2, 1024, 1024, 1024, 1024);
  ln_k<<<dim3(8192), b256, 0, stream>>>(x2, ln2g, ln2b, xn);
  // FF in two K-slices of 2048 so hbuf (8192x2048) fits in v+pooled region
  gemm_k<true, true, false, true><<<dim3(16, 64), b256, 0, stream>>>(
      xn, w1T, b1, nullptr, hbuf, 1024, 2048, 1024, 1024);
  gemm_k<false, false, true, true><<<dim3(8, 64), b256, 0, stream>>>(
      hbuf, w2T, b2, x2, x2, 2048, 1024, 2048, 4096);
  gemm_k<true, true, false, true><<<dim3(16, 64), b256, 0, stream>>>(
      xn, w1T + (size_t)2048 * 1024, b1 + 2048, nullptr, hbuf, 1024, 2048,
      1024, 1024);
  gemm_k<false, false, true, false><<<dim3(8, 64), b256, 0, stream>>>(
      hbuf, w2T + 2048, nullptr, x2, x2, 2048, 1024, 2048, 4096);
}

// Round 6
// 538.631 us; speedup vs baseline: 1.3092x; 1.3092x over previous
//
#include <hip/hip_runtime.h>
#include <hip/hip_bf16.h>

typedef float fv4 __attribute__((ext_vector_type(4)));
typedef __bf16 bfv8 __attribute__((ext_vector_type(8)));
typedef unsigned short u16;

#define DEV static __device__ __forceinline__

DEV u16 f2bf(float f) {
  union { __hip_bfloat16 h; u16 u; } c;
  c.h = __float2bfloat16(f);
  return c.u;
}

DEV void glds16(const void* g, void* l) {
  __builtin_amdgcn_global_load_lds(
      (const __attribute__((address_space(1))) unsigned int*)g,
      (__attribute__((address_space(3))) unsigned int*)l, 16, 0, 0);
}

DEV fv4 mfma16(bfv8 a, bfv8 b, fv4 c) {
  return __builtin_amdgcn_mfma_f32_16x16x32_bf16(a, b, c, 0, 0, 0);
}

// ---------------------------------------------------------------------------
// GEMM: C[MrxN] = A[Mr x K](bf16, row stride lda) @ Bt[N x K](bf16, stride
// ldb)^T + bias (+resid, relu). 128x128 tile, BK=32, 4 waves, 4x4 frags.
// LDS XOR-swizzle (row&7)<<4 via pre-swizzled global_load_lds source.
// ---------------------------------------------------------------------------
template <bool OUT_BF16, bool RELU, bool RESID, bool BIAS>
__global__ __launch_bounds__(256, 2) void gemm_k(
    const u16* __restrict__ A, const u16* __restrict__ Bt,
    const float* __restrict__ bias, const float* __restrict__ resid,
    void* __restrict__ outp, int K, int N, int lda, int ldb) {
  __shared__ __align__(16) u16 lds[2][2][128 * 32];
  const int tid = threadIdx.x;
  const int lane = tid & 63, wid = tid >> 6;
  const int bm0 = blockIdx.y * 128, bn0 = blockIdx.x * 128;
  const int wr = (wid >> 1) * 64, wc = (wid & 1) * 64;
  const int g = lane >> 4, ml = lane & 15;

  fv4 acc[4][4];
#pragma unroll
  for (int i = 0; i < 4; ++i)
#pragma unroll
    for (int j = 0; j < 4; ++j) acc[i][j] = (fv4)0.f;

  const int nK = K >> 5;

  auto stage = [&](int t) {
    const int buf = t & 1;
    const int k0 = t * 32;
#pragma unroll
    for (int p = 0; p < 2; ++p) {
      const int s = p * 256 + tid;
      const int r0 = ((s >> 2) & 1) ^ ((s >> 4) & 1);
      const int row = ((s >> 3) << 1) | r0;
      const int chunk = (s & 3) ^ (row & 3);
      glds16(A + (size_t)(bm0 + row) * lda + k0 + chunk * 8,
             &lds[buf][0][(p * 256 + wid * 64) * 8]);
      glds16(Bt + (size_t)(bn0 + row) * ldb + k0 + chunk * 8,
             &lds[buf][1][(p * 256 + wid * 64) * 8]);
    }
  };

  stage(0);
  for (int t = 0; t < nK; ++t) {
    __syncthreads();
    if (t + 1 < nK) stage(t + 1);
    const u16* Ab = lds[t & 1][0];
    const u16* Bb = lds[t & 1][1];
    bfv8 af[4], bf[4];
#pragma unroll
    for (int f = 0; f < 4; ++f) {
      const int ra = wr + f * 16 + ml;
      const int ba = ((ra << 6) + (g << 4)) ^ ((ra & 7) << 4);
      af[f] = *(const bfv8*)&Ab[ba >> 1];
      const int rb = wc + f * 16 + ml;
      const int bb = ((rb << 6) + (g << 4)) ^ ((rb & 7) << 4);
      bf[f] = *(const bfv8*)&Bb[bb >> 1];
    }
#pragma unroll
    for (int i = 0; i < 4; ++i)
#pragma unroll
      for (int j = 0; j < 4; ++j) acc[i][j] = mfma16(af[i], bf[j], acc[i][j]);
  }

#pragma unroll
  for (int j = 0; j < 4; ++j) {
    const int n = bn0 + wc + j * 16 + ml;
    float bv = 0.f;
    if (BIAS) bv = bias[n];
#pragma unroll
    for (int i = 0; i < 4; ++i) {
      const int m0r = bm0 + wr + i * 16 + g * 4;
#pragma unroll
      for (int r = 0; r < 4; ++r) {
        float val = acc[i][j][r] + bv;
        if (RESID) val += resid[(size_t)(m0r + r) * N + n];
        if (RELU) val = fmaxf(val, 0.f);
        if (OUT_BF16)
          ((u16*)outp)[(size_t)(m0r + r) * N + n] = f2bf(val);
        else
          ((float*)outp)[(size_t)(m0r + r) * N + n] = val;
      }
    }
  }
}

// ---------------------------------------------------------------------------
// Attention with rank-1 logits: logits[m,n] = qs[m]*ks[n]; softmax over n;
// pooled = W @ V. Block: one (b,h), 64 m-rows, 4 waves x 16 rows.
// ---------------------------------------------------------------------------
__global__ __launch_bounds__(256, 2) void attn2_k(
    const u16* __restrict__ v, const float* __restrict__ qsarr,
    const float* __restrict__ ksarr, const unsigned char* __restrict__ mask,
    u16* __restrict__ pooled) {
  __shared__ float ks_s[1024];
  __shared__ float red[16];
  __shared__ int anym_s;
  __shared__ float zl[4][16];
  __shared__ __align__(16) u16 VT[64 * 72];

  const int tid = threadIdx.x, lane = tid & 63, wid = tid >> 6;
  const int g = lane >> 4, ml = lane & 15;
  const int b = blockIdx.y >> 4, h = blockIdx.y & 15;
  const int m0 = blockIdx.x * 64;

  if (tid == 0) anym_s = 0;
  __syncthreads();

  const float* ksp = ksarr + (size_t)(b * 16 + h) * 1024;
  float4 kv = *(const float4*)&ksp[tid * 4];
  *(float4*)&ks_s[tid * 4] = kv;
  const float kvv[4] = {kv.x, kv.y, kv.z, kv.w};
  float mx = -3.4e38f, mn = 3.4e38f;
  int am = 0;
#pragma unroll
  for (int j = 0; j < 4; ++j) {
    const int n = tid * 4 + j;
    const int mk = mask[(size_t)n * 8 + b] ? 1 : 0;
    am |= mk;
    if (!mk) { mx = fmaxf(mx, kvv[j]); mn = fminf(mn, kvv[j]); }
  }
  if (am) atomicOr(&anym_s, 1);
#pragma unroll
  for (int s = 1; s <= 32; s <<= 1) {
    mx = fmaxf(mx, __shfl_xor(mx, s, 64));
    mn = fminf(mn, __shfl_xor(mn, s, 64));
  }
  if (lane == 0) { red[wid] = mx; red[8 + wid] = mn; }
  __syncthreads();
  const float smax = fmaxf(fmaxf(red[0], red[1]), fmaxf(red[2], red[3]));
  const float smin = fminf(fminf(red[8], red[9]), fminf(red[10], red[11]));
  const int anym = anym_s;

  const float c = qsarr[(size_t)(b * 16 + h) * 1024 + m0 + wid * 16 + ml];
  const float M = (c >= 0.f) ? c * smax : c * smin;  // M >= 0 always

  fv4 o[4];
#pragma unroll
  for (int d = 0; d < 4; ++d) o[d] = (fv4)0.f;
  float zacc = 0.f;

  for (int nt = 0; nt < 16; ++nt) {
    const int n0 = nt * 64;
    if (nt) __syncthreads();
#pragma unroll
    for (int p = 0; p < 2; ++p) {
      const int s = p * 256 + tid;
      const int n = s >> 3, cc = s & 7;
      bfv8 vv = *(const bfv8*)&v[((size_t)(n0 + n) * 8 + b) * 1024 + h * 64 + cc * 8];
      const u16* vb = (const u16*)&vv;
#pragma unroll
      for (int j = 0; j < 8; ++j) VT[(cc * 8 + j) * 72 + n] = vb[j];
    }
    __syncthreads();

    bfv8 pa[2];
#pragma unroll
    for (int kk = 0; kk < 2; ++kk) {
      const int kb = n0 + kk * 32 + g * 8;
      const float4 s0 = *(const float4*)&ks_s[kb - n0 + n0];
      const float4 s1 = *(const float4*)&ks_s[kb + 4];
      const float sv[8] = {s0.x, s0.y, s0.z, s0.w, s1.x, s1.y, s1.z, s1.w};
      u16 tmp[8];
#pragma unroll
      for (int j = 0; j < 8; ++j) {
        float p = __expf(fmaf(c, sv[j], -M));
        if (anym && mask[(size_t)(kb + j) * 8 + b]) p = 0.f;
        zacc += p;
        tmp[j] = f2bf(p);
      }
      pa[kk] = *(const bfv8*)tmp;
    }
#pragma unroll
    for (int kk = 0; kk < 2; ++kk)
#pragma unroll
      for (int ds = 0; ds < 4; ++ds) {
        bfv8 vf = *(const bfv8*)&VT[(ds * 16 + ml) * 72 + kk * 32 + g * 8];
        o[ds] = mfma16(pa[kk], vf, o[ds]);
      }
  }

  zacc += __shfl_xor(zacc, 16, 64);
  zacc += __shfl_xor(zacc, 32, 64);
  if (g == 0) zl[wid][ml] = zacc;
  asm volatile("" ::: "memory");
  float zin[4];
#pragma unroll
  for (int r = 0; r < 4; ++r) zin[r] = 1.f / zl[wid][g * 4 + r];

  __syncthreads();
  u16* stg = &VT[wid * 16 * 72];
#pragma unroll
  for (int ds = 0; ds < 4; ++ds)
#pragma unroll
    for (int r = 0; r < 4; ++r)
      stg[(g * 4 + r) * 72 + ds * 16 + ml] = f2bf(o[ds][r] * zin[r]);
  asm volatile("" ::: "memory");
#pragma unroll
  for (int p = 0; p < 2; ++p) {
    const int ch = p * 64 + lane;
    const int mr = ch >> 3, cc = ch & 7;
    bfv8 val = *(const bfv8*)&stg[mr * 72 + cc * 8];
    *(bfv8*)&pooled[((size_t)(m0 + wid * 16 + mr) * 8 + b) * 1024 + h * 64 + cc * 8] = val;
  }
}

// ---------------------------------------------------------------------------
// LayerNorm: one block per row of 1024, fp32 in -> bf16 out
// ---------------------------------------------------------------------------
__global__ __launch_bounds__(256) void ln_k(
    const float* __restrict__ x, const float* __restrict__ gw,
    const float* __restrict__ bw, u16* __restrict__ out) {
  __shared__ float sm[8];
  const int row = blockIdx.x, tid = threadIdx.x;
  const int lane = tid & 63, wid = tid >> 6;
  const float4 xv = *(const float4*)&x[(size_t)row * 1024 + tid * 4];
  float s = xv.x + xv.y + xv.z + xv.w;
  float q = xv.x * xv.x + xv.y * xv.y + xv.z * xv.z + xv.w * xv.w;
#pragma unroll
  for (int m = 1; m <= 32; m <<= 1) {
    s += __shfl_xor(s, m, 64);
    q += __shfl_xor(q, m, 64);
  }
  if (lane == 0) { sm[wid] = s; sm[4 + wid] = q; }
  __syncthreads();
  s = sm[0] + sm[1] + sm[2] + sm[3];
  q = sm[4] + sm[5] + sm[6] + sm[7];
  const float mean = s * (1.f / 1024.f);
  const float var = q * (1.f / 1024.f) - mean * mean;
  const float rstd = rsqrtf(var + 1e-5f);
  const float4 gv = *(const float4*)&gw[tid * 4];
  const float4 bv = *(const float4*)&bw[tid * 4];
  ushort4 ov;
  ov.x = f2bf((xv.x - mean) * rstd * gv.x + bv.x);
  ov.y = f2bf((xv.y - mean) * rstd * gv.y + bv.y);
  ov.z = f2bf((xv.z - mean) * rstd * gv.z + bv.z);
  ov.w = f2bf((xv.w - mean) * rstd * gv.w + bv.w);
  *(ushort4*)&out[(size_t)row * 1024 + tid * 4] = ov;
}

// ---------------------------------------------------------------------------
// qks2: C[16 rows][32] = X[16x1024] @ A[1024x32] with LN folded into A:
// qs_h = rstd*(dot_h - mu*S1_h) + S2_h. Block: 256 threads, 16 rows.
// Thread: rowpair = t&7 (2 rows), sub = t>>3 (4 k per 128-k chunk).
// A chunk staged in LDS stride 36 (16B-aligned, bank-spread).
// ---------------------------------------------------------------------------
__global__ __launch_bounds__(256) void qks2_k(
    const float* __restrict__ x, const float* __restrict__ A,
    const float* __restrict__ S12, float* __restrict__ qsarr,
    float* __restrict__ ksarr) {
  __shared__ __align__(16) float Alds[128 * 36];
  __shared__ float wred[4][8][2][32];
  __shared__ float wred2[4][8][2][2];
  __shared__ float rowstat[16][2];

  const int t = threadIdx.x;
  const int rowp = t & 7, sub = t >> 3;
  const int wid = t >> 6, lane = t & 63;
  const int r0 = blockIdx.x * 16;

  float acc[2][32];
#pragma unroll
  for (int rr = 0; rr < 2; ++rr)
#pragma unroll
    for (int i = 0; i < 32; ++i) acc[rr][i] = 0.f;
  float sx[2] = {0.f, 0.f}, sq[2] = {0.f, 0.f};

  for (int ch = 0; ch < 8; ++ch) {
    __syncthreads();
#pragma unroll
    for (int j = 0; j < 4; ++j) {
      const int f = t + 256 * j;
      const float4 av = *(const float4*)&A[ch * 4096 + f * 4];
      *(float4*)&Alds[(f >> 3) * 36 + (f & 7) * 4] = av;
    }
    __syncthreads();
#pragma unroll
    for (int rr = 0; rr < 2; ++rr) {
      const int row = r0 + rowp * 2 + rr;
      const float4 xv = *(const float4*)&x[(size_t)row * 1024 + ch * 128 + sub * 4];
      const float xs[4] = {xv.x, xv.y, xv.z, xv.w};
#pragma unroll
      for (int kk = 0; kk < 4; ++kk) {
        sx[rr] += xs[kk];
        sq[rr] = fmaf(xs[kk], xs[kk], sq[rr]);
        const float* ap = &Alds[(sub * 4 + kk) * 36];
#pragma unroll
        for (int i = 0; i < 32; ++i)
          acc[rr][i] = fmaf(xs[kk], ap[i], acc[rr][i]);
      }
    }
  }

  // reduce across the 8 subs within each wave (lane bits 3..5)
#pragma unroll
  for (int m = 8; m <= 32; m <<= 1) {
#pragma unroll
    for (int rr = 0; rr < 2; ++rr) {
      sx[rr] += __shfl_xor(sx[rr], m, 64);
      sq[rr] += __shfl_xor(sq[rr], m, 64);
#pragma unroll
      for (int i = 0; i < 32; ++i)
        acc[rr][i] += __shfl_xor(acc[rr][i], m, 64);
    }
  }
  if (lane < 8) {
#pragma unroll
    for (int rr = 0; rr < 2; ++rr) {
#pragma unroll
      for (int i = 0; i < 32; ++i) wred[wid][lane][rr][i] = acc[rr][i];
      wred2[wid][lane][rr][0] = sx[rr];
      wred2[wid][lane][rr][1] = sq[rr];
    }
  }
  __syncthreads();

  if (t < 16) {
    float s = 0.f, q = 0.f;
#pragma unroll
    for (int w = 0; w < 4; ++w) {
      s += wred2[w][t >> 1][t & 1][0];
      q += wred2[w][t >> 1][t & 1][1];
    }
    const float mu = s * (1.f / 1024.f);
    const float var = q * (1.f / 1024.f) - mu * mu;
    rowstat[t][0] = mu;
    rowstat[t][1] = rsqrtf(var + 1e-5f);
  }
  __syncthreads();

#pragma unroll
  for (int o = 0; o < 2; ++o) {
    const int idx = t * 2 + o;
    const int rl = idx >> 5, h = idx & 31;
    const float dot = wred[0][rl >> 1][rl & 1][h] + wred[1][rl >> 1][rl & 1][h] +
                      wred[2][rl >> 1][rl & 1][h] + wred[3][rl >> 1][rl & 1][h];
    const float mu = rowstat[rl][0], rstd = rowstat[rl][1];
    const float val = rstd * (dot - mu * S12[h]) + S12[32 + h];
    const int row = r0 + rl, mm = row >> 3, bb = row & 7;
    if (h < 16)
      qsarr[(size_t)(bb * 16 + h) * 1024 + mm] = val;
    else
      ksarr[(size_t)(bb * 16 + h - 16) * 1024 + mm] = val;
  }
}

// wqsa[k][h32] = sum over the 64 in-head cols of wq (h32<16) / wk (h32>=16)
__global__ void wsum_k(const float* __restrict__ wq,
                       const float* __restrict__ wk,
                       float* __restrict__ wqsa) {
  const int k = blockIdx.x, t = threadIdx.x;
  const int h32 = t >> 3, ch = t & 7;
  const float* src = (h32 < 16) ? (wq + (size_t)k * 1024 + h32 * 64 + ch * 8)
                                : (wk + (size_t)k * 1024 + (h32 - 16) * 64 + ch * 8);
  float s = 0.f;
#pragma unroll
  for (int j = 0; j < 8; ++j) s += src[j];
  s += __shfl_xor(s, 1, 64);
  s += __shfl_xor(s, 2, 64);
  s += __shfl_xor(s, 4, 64);
  if (ch == 0) wqsa[k * 32 + h32] = s;
}

__global__ void bsum_k(const float* __restrict__ bq,
                       const float* __restrict__ bk,
                       float* __restrict__ bqks) {
  const int t = threadIdx.x;
  if (t < 32) {
    const float* s = (t < 16) ? (bq + t * 64) : (bk + (t - 16) * 64);
    float a = 0.f;
    for (int j = 0; j < 64; ++j) a += s[j];
    bqks[t] = a;
  }
}

// A[k][h] = ln1g[k] * wqsa[k][h]  (8192 float4s over grid 32x256)
__global__ void afill_k(const float* __restrict__ wqsa,
                        const float* __restrict__ g,
                        float* __restrict__ A) {
  const int f = blockIdx.x * 256 + threadIdx.x;
  const float gv = g[f >> 3];
  const float4 wv = *(const float4*)&wqsa[f * 4];
  float4 av;
  av.x = wv.x * gv; av.y = wv.y * gv; av.z = wv.z * gv; av.w = wv.w * gv;
  *(float4*)&A[f * 4] = av;
}

// S12[h] = sum_k g[k]*wqsa[k][h]; S12[32+h] = sum_k lb[k]*wqsa[k][h] + bqks[h]
__global__ void s12_k(const float* __restrict__ wqsa,
                      const float* __restrict__ g,
                      const float* __restrict__ lb,
                      const float* __restrict__ bqks,
                      float* __restrict__ S12) {
  __shared__ float red1[8][32], red2[8][32];
  const int t = threadIdx.x;
  const int h = t & 31, seg = t >> 5;
  float s1 = 0.f, s2 = 0.f;
  for (int k = seg * 128; k < seg * 128 + 128; ++k) {
    const float a = wqsa[k * 32 + h];
    s1 = fmaf(g[k], a, s1);
    s2 = fmaf(lb[k], a, s2);
  }
  red1[seg][h] = s1;
  red2[seg][h] = s2;
  __syncthreads();
  if (t < 32) {
    float a1 = 0.f, a2 = 0.f;
#pragma unroll
    for (int s = 0; s < 8; ++s) { a1 += red1[s][t]; a2 += red2[s][t]; }
    S12[t] = a1;
    S12[32 + t] = a2 + bqks[t];
  }
}

// W (RxC fp32) -> Wt (CxR bf16)
__global__ void tr_k(const float* __restrict__ W, u16* __restrict__ Wt,
                     int R, int C) {
  __shared__ float tile[32][33];
  const int x = threadIdx.x, y = threadIdx.y;
  const int c0 = blockIdx.x * 32, r0 = blockIdx.y * 32;
#pragma unroll
  for (int i = 0; i < 4; ++i)
    tile[y + i * 8][x] = W[(size_t)(r0 + y + i * 8) * C + c0 + x];
  __syncthreads();
#pragma unroll
  for (int i = 0; i < 4; ++i)
    Wt[(size_t)(c0 + y + i * 8) * R + r0 + x] = f2bf(tile[x][y + i * 8]);
}

extern "C" void kernel_launch(void* const* d_in, const int* in_sizes, int n_in,
                              void* d_out, int out_size, void* d_ws,
                              size_t ws_size, hipStream_t stream) {
  const float* x = (const float*)d_in[0];
  const unsigned char* mask = (const unsigned char*)d_in[1];
  const float* ln1g = (const float*)d_in[2];
  const float* ln1b = (const float*)d_in[3];
  const float* wq = (const float*)d_in[4];
  const float* bq = (const float*)d_in[5];
  const float* wk = (const float*)d_in[6];
  const float* bk = (const float*)d_in[7];
  const float* wv = (const float*)d_in[8];
  const float* bv = (const float*)d_in[9];
  const float* wo = (const float*)d_in[10];
  const float* bo = (const float*)d_in[11];
  const float* ln2g = (const float*)d_in[12];
  const float* ln2b = (const float*)d_in[13];
  const float* w1 = (const float*)d_in[14];
  const float* b1 = (const float*)d_in[15];
  const float* w2 = (const float*)d_in[16];
  const float* b2 = (const float*)d_in[17];

  // ---- workspace layout (~69.3 MB) ----
  u16* wvT = (u16*)d_ws;                        // 1024x1024 bf16
  u16* woT = wvT + 1024 * 1024;                 // 1024x1024
  u16* w1T = woT + 1024 * 1024;                 // 4096x1024
  u16* w2T = w1T + 4096 * 1024;                 // 1024x4096
  float* wqsa = (float*)(w2T + 1024 * 4096);    // [1024][32] f32
  float* bqks = wqsa + 1024 * 32;               // 32 f32
  float* Aq = bqks + 32;                        // [1024][32] f32 (g-folded)
  float* S12 = Aq + 1024 * 32;                  // 64 f32
  float* qsarr = S12 + 64;                      // [8][16][1024] f32
  float* ksarr = qsarr + 8 * 16 * 1024;         // [8][16][1024] f32
  u16* v = (u16*)(ksarr + 8 * 16 * 1024);       // 8192x1024 bf16
  u16* pooled = v + (size_t)8192 * 1024;        // 8192x1024 bf16
  u16* xn = pooled + (size_t)8192 * 1024;       // 8192x1024 bf16
  u16* hbuf = v;                                // alias: 8192x2048 (v+pooled)
  float* x2 = (float*)d_out;                    // fp32 residual in d_out

  const dim3 b256(256), btr(32, 8);
  tr_k<<<dim3(32, 32), btr, 0, stream>>>(wv, wvT, 1024, 1024);
  tr_k<<<dim3(32, 32), btr, 0, stream>>>(wo, woT, 1024, 1024);
  tr_k<<<dim3(128, 32), btr, 0, stream>>>(w1, w1T, 1024, 4096);
  tr_k<<<dim3(32, 128), btr, 0, stream>>>(w2, w2T, 4096, 1024);
  wsum_k<<<dim3(1024), b256, 0, stream>>>(wq, wk, wqsa);
  bsum_k<<<dim3(1), dim3(64), 0, stream>>>(bq, bk, bqks);
  afill_k<<<dim3(32), b256, 0, stream>>>(wqsa, ln1g, Aq);
  s12_k<<<dim3(1), b256, 0, stream>>>(wqsa, ln1g, ln1b, bqks, S12);

  ln_k<<<dim3(8192), b256, 0, stream>>>(x, ln1g, ln1b, xn);
  qks2_k<<<dim3(512), b256, 0, stream>>>(x, Aq, S12, qsarr, ksarr);
  gemm_k<true, false, false, true><<<dim3(8, 64), b256, 0, stream>>>(
      xn, wvT, bv, nullptr, v, 1024, 1024, 1024, 1024);
  attn2_k<<<dim3(16, 128), b256, 0, stream>>>(v, qsarr, ksarr, mask, pooled);
  gemm_k<false, false, true, true><<<dim3(8, 64), b256, 0, stream>>>(
      pooled, woT, bo, x, x2, 1024, 1024, 1024, 1024);
  ln_k<<<dim3(8192), b256, 0, stream>>>(x2, ln2g, ln2b, xn);
  // FF in two K-slices of 2048 so hbuf (8192x2048) fits in v+pooled region
  gemm_k<true, true, false, true><<<dim3(16, 64), b256, 0, stream>>>(
      xn, w1T, b1, nullptr, hbuf, 1024, 2048, 1024, 1024);
  gemm_k<false, false, true, true><<<dim3(8, 64), b256, 0, stream>>>(
      hbuf, w2T, b2, x2, x2, 2048, 1024, 2048, 4096);
  gemm_k<true, true, false, true><<<dim3(16, 64), b256, 0, stream>>>(
      xn, w1T + (size_t)2048 * 1024, b1 + 2048, nullptr, hbuf, 1024, 2048,
      1024, 1024);
  gemm_k<false, false, true, false><<<dim3(8, 64), b256, 0, stream>>>(
      hbuf, w2T + 2048, nullptr, x2, x2, 2048, 1024, 2048, 4096);
}

// Round 7
// 504.889 us; speedup vs baseline: 1.3967x; 1.0668x over previous
//
#include <hip/hip_runtime.h>
#include <hip/hip_bf16.h>

typedef float fv4 __attribute__((ext_vector_type(4)));
typedef __bf16 bfv8 __attribute__((ext_vector_type(8)));
typedef unsigned short u16;

#define DEV static __device__ __forceinline__

DEV u16 f2bf(float f) {
  union { __hip_bfloat16 h; u16 u; } c;
  c.h = __float2bfloat16(f);
  return c.u;
}

DEV void glds16(const void* g, void* l) {
  __builtin_amdgcn_global_load_lds(
      (const __attribute__((address_space(1))) unsigned int*)g,
      (__attribute__((address_space(3))) unsigned int*)l, 16, 0, 0);
}

DEV fv4 mfma16(bfv8 a, bfv8 b, fv4 c) {
  return __builtin_amdgcn_mfma_f32_16x16x32_bf16(a, b, c, 0, 0, 0);
}

// ---------------------------------------------------------------------------
// GEMM: C[MrxN] = A[Mr x K](bf16, row stride lda) @ Bt[N x K](bf16, stride
// ldb)^T + bias (+resid, relu). 128x128 tile, BK=32, 4 waves, 4x4 frags.
// LDS XOR-swizzle (row&7)<<4 via pre-swizzled global_load_lds source.
// ---------------------------------------------------------------------------
template <bool OUT_BF16, bool RELU, bool RESID, bool BIAS>
__global__ __launch_bounds__(256, 2) void gemm_k(
    const u16* __restrict__ A, const u16* __restrict__ Bt,
    const float* __restrict__ bias, const float* __restrict__ resid,
    void* __restrict__ outp, int K, int N, int lda, int ldb) {
  __shared__ __align__(16) u16 lds[2][2][128 * 32];
  const int tid = threadIdx.x;
  const int lane = tid & 63, wid = tid >> 6;
  const int bm0 = blockIdx.y * 128, bn0 = blockIdx.x * 128;
  const int wr = (wid >> 1) * 64, wc = (wid & 1) * 64;
  const int g = lane >> 4, ml = lane & 15;

  fv4 acc[4][4];
#pragma unroll
  for (int i = 0; i < 4; ++i)
#pragma unroll
    for (int j = 0; j < 4; ++j) acc[i][j] = (fv4)0.f;

  const int nK = K >> 5;

  auto stage = [&](int t) {
    const int buf = t & 1;
    const int k0 = t * 32;
#pragma unroll
    for (int p = 0; p < 2; ++p) {
      const int s = p * 256 + tid;
      const int r0 = ((s >> 2) & 1) ^ ((s >> 4) & 1);
      const int row = ((s >> 3) << 1) | r0;
      const int chunk = (s & 3) ^ (row & 3);
      glds16(A + (size_t)(bm0 + row) * lda + k0 + chunk * 8,
             &lds[buf][0][(p * 256 + wid * 64) * 8]);
      glds16(Bt + (size_t)(bn0 + row) * ldb + k0 + chunk * 8,
             &lds[buf][1][(p * 256 + wid * 64) * 8]);
    }
  };

  stage(0);
  for (int t = 0; t < nK; ++t) {
    __syncthreads();
    if (t + 1 < nK) stage(t + 1);
    const u16* Ab = lds[t & 1][0];
    const u16* Bb = lds[t & 1][1];
    bfv8 af[4], bf[4];
#pragma unroll
    for (int f = 0; f < 4; ++f) {
      const int ra = wr + f * 16 + ml;
      const int ba = ((ra << 6) + (g << 4)) ^ ((ra & 7) << 4);
      af[f] = *(const bfv8*)&Ab[ba >> 1];
      const int rb = wc + f * 16 + ml;
      const int bb = ((rb << 6) + (g << 4)) ^ ((rb & 7) << 4);
      bf[f] = *(const bfv8*)&Bb[bb >> 1];
    }
#pragma unroll
    for (int i = 0; i < 4; ++i)
#pragma unroll
      for (int j = 0; j < 4; ++j) acc[i][j] = mfma16(af[i], bf[j], acc[i][j]);
  }

#pragma unroll
  for (int j = 0; j < 4; ++j) {
    const int n = bn0 + wc + j * 16 + ml;
    float bv = 0.f;
    if (BIAS) bv = bias[n];
#pragma unroll
    for (int i = 0; i < 4; ++i) {
      const int m0r = bm0 + wr + i * 16 + g * 4;
#pragma unroll
      for (int r = 0; r < 4; ++r) {
        float val = acc[i][j][r] + bv;
        if (RESID) val += resid[(size_t)(m0r + r) * N + n];
        if (RELU) val = fmaxf(val, 0.f);
        if (OUT_BF16)
          ((u16*)outp)[(size_t)(m0r + r) * N + n] = f2bf(val);
        else
          ((float*)outp)[(size_t)(m0r + r) * N + n] = val;
      }
    }
  }
}

// ---------------------------------------------------------------------------
// Attention with rank-1 logits: logits[m,n] = qs[m]*ks[n]; softmax over n;
// pooled = W @ V. Block: one (b,h), 64 m-rows, 4 waves x 16 rows.
// VT staging uses XOR col-swizzle col' = n ^ ((row>>3)<<3): write side goes
// 16-way-conflict -> 2-way (free); b128 read side stays uniform.
// ---------------------------------------------------------------------------
__global__ __launch_bounds__(256, 2) void attn2_k(
    const u16* __restrict__ v, const float* __restrict__ qsarr,
    const float* __restrict__ ksarr, const unsigned char* __restrict__ mask,
    u16* __restrict__ pooled) {
  __shared__ float ks_s[1024];
  __shared__ float red[16];
  __shared__ int anym_s;
  __shared__ float zl[4][16];
  __shared__ __align__(16) u16 VT[64 * 72];

  const int tid = threadIdx.x, lane = tid & 63, wid = tid >> 6;
  const int g = lane >> 4, ml = lane & 15;
  const int b = blockIdx.y >> 4, h = blockIdx.y & 15;
  const int m0 = blockIdx.x * 64;

  if (tid == 0) anym_s = 0;
  __syncthreads();

  const float* ksp = ksarr + (size_t)(b * 16 + h) * 1024;
  float4 kv = *(const float4*)&ksp[tid * 4];
  *(float4*)&ks_s[tid * 4] = kv;
  const float kvv[4] = {kv.x, kv.y, kv.z, kv.w};
  float mx = -3.4e38f, mn = 3.4e38f;
  int am = 0;
#pragma unroll
  for (int j = 0; j < 4; ++j) {
    const int n = tid * 4 + j;
    const int mk = mask[(size_t)n * 8 + b] ? 1 : 0;
    am |= mk;
    if (!mk) { mx = fmaxf(mx, kvv[j]); mn = fminf(mn, kvv[j]); }
  }
  if (am) atomicOr(&anym_s, 1);
#pragma unroll
  for (int s = 1; s <= 32; s <<= 1) {
    mx = fmaxf(mx, __shfl_xor(mx, s, 64));
    mn = fminf(mn, __shfl_xor(mn, s, 64));
  }
  if (lane == 0) { red[wid] = mx; red[8 + wid] = mn; }
  __syncthreads();
  const float smax = fmaxf(fmaxf(red[0], red[1]), fmaxf(red[2], red[3]));
  const float smin = fminf(fminf(red[8], red[9]), fminf(red[10], red[11]));
  const int anym = anym_s;

  const float c = qsarr[(size_t)(b * 16 + h) * 1024 + m0 + wid * 16 + ml];
  const float M = (c >= 0.f) ? c * smax : c * smin;  // M >= 0 always

  fv4 o[4];
#pragma unroll
  for (int d = 0; d < 4; ++d) o[d] = (fv4)0.f;
  float zacc = 0.f;

  for (int nt = 0; nt < 16; ++nt) {
    const int n0 = nt * 64;
    if (nt) __syncthreads();
    // stage V transposed: VT[d][n ^ ((d>>3)<<3)], stride 72
#pragma unroll
    for (int p = 0; p < 2; ++p) {
      const int s = p * 256 + tid;
      const int n = s >> 3, cc = s & 7;
      bfv8 vv = *(const bfv8*)&v[((size_t)(n0 + n) * 8 + b) * 1024 + h * 64 + cc * 8];
      const u16* vb = (const u16*)&vv;
      const int nsw = n ^ (cc << 3);  // row>>3 == cc for rows cc*8+j
#pragma unroll
      for (int j = 0; j < 8; ++j) VT[(cc * 8 + j) * 72 + nsw] = vb[j];
    }
    __syncthreads();

    bfv8 pa[2];
#pragma unroll
    for (int kk = 0; kk < 2; ++kk) {
      const int kb = n0 + kk * 32 + g * 8;
      const float4 s0 = *(const float4*)&ks_s[kb];
      const float4 s1 = *(const float4*)&ks_s[kb + 4];
      const float sv[8] = {s0.x, s0.y, s0.z, s0.w, s1.x, s1.y, s1.z, s1.w};
      u16 tmp[8];
#pragma unroll
      for (int j = 0; j < 8; ++j) {
        float p = __expf(fmaf(c, sv[j], -M));
        if (anym && mask[(size_t)(kb + j) * 8 + b]) p = 0.f;
        zacc += p;
        tmp[j] = f2bf(p);
      }
      pa[kk] = *(const bfv8*)tmp;
    }
#pragma unroll
    for (int kk = 0; kk < 2; ++kk)
#pragma unroll
      for (int ds = 0; ds < 4; ++ds) {
        const int rb = ds * 16 + ml;
        const int cb = (kk * 32 + g * 8) ^ ((rb >> 3) << 3);
        bfv8 vf = *(const bfv8*)&VT[rb * 72 + cb];
        o[ds] = mfma16(pa[kk], vf, o[ds]);
      }
  }

  zacc += __shfl_xor(zacc, 16, 64);
  zacc += __shfl_xor(zacc, 32, 64);
  if (g == 0) zl[wid][ml] = zacc;
  asm volatile("" ::: "memory");
  float zin[4];
#pragma unroll
  for (int r = 0; r < 4; ++r) zin[r] = 1.f / zl[wid][g * 4 + r];

  __syncthreads();
  u16* stg = &VT[wid * 16 * 72];
#pragma unroll
  for (int ds = 0; ds < 4; ++ds)
#pragma unroll
    for (int r = 0; r < 4; ++r)
      stg[(g * 4 + r) * 72 + ds * 16 + ml] = f2bf(o[ds][r] * zin[r]);
  asm volatile("" ::: "memory");
#pragma unroll
  for (int p = 0; p < 2; ++p) {
    const int ch = p * 64 + lane;
    const int mr = ch >> 3, cc = ch & 7;
    bfv8 val = *(const bfv8*)&stg[mr * 72 + cc * 8];
    *(bfv8*)&pooled[((size_t)(m0 + wid * 16 + mr) * 8 + b) * 1024 + h * 64 + cc * 8] = val;
  }
}

// ---------------------------------------------------------------------------
// LayerNorm: one block per row of 1024, fp32 in -> bf16 out
// ---------------------------------------------------------------------------
__global__ __launch_bounds__(256) void ln_k(
    const float* __restrict__ x, const float* __restrict__ gw,
    const float* __restrict__ bw, u16* __restrict__ out) {
  __shared__ float sm[8];
  const int row = blockIdx.x, tid = threadIdx.x;
  const int lane = tid & 63, wid = tid >> 6;
  const float4 xv = *(const float4*)&x[(size_t)row * 1024 + tid * 4];
  float s = xv.x + xv.y + xv.z + xv.w;
  float q = xv.x * xv.x + xv.y * xv.y + xv.z * xv.z + xv.w * xv.w;
#pragma unroll
  for (int m = 1; m <= 32; m <<= 1) {
    s += __shfl_xor(s, m, 64);
    q += __shfl_xor(q, m, 64);
  }
  if (lane == 0) { sm[wid] = s; sm[4 + wid] = q; }
  __syncthreads();
  s = sm[0] + sm[1] + sm[2] + sm[3];
  q = sm[4] + sm[5] + sm[6] + sm[7];
  const float mean = s * (1.f / 1024.f);
  const float var = q * (1.f / 1024.f) - mean * mean;
  const float rstd = rsqrtf(var + 1e-5f);
  const float4 gv = *(const float4*)&gw[tid * 4];
  const float4 bv = *(const float4*)&bw[tid * 4];
  ushort4 ov;
  ov.x = f2bf((xv.x - mean) * rstd * gv.x + bv.x);
  ov.y = f2bf((xv.y - mean) * rstd * gv.y + bv.y);
  ov.z = f2bf((xv.z - mean) * rstd * gv.z + bv.z);
  ov.w = f2bf((xv.w - mean) * rstd * gv.w + bv.w);
  *(ushort4*)&out[(size_t)row * 1024 + tid * 4] = ov;
}

// ---------------------------------------------------------------------------
// qks2: C[16 rows][32] = X[16x1024] @ A[1024x32] with LN folded into A:
// qs_h = rstd*(dot_h - mu*S1_h) + S2_h. Block: 256 threads, 16 rows.
// ---------------------------------------------------------------------------
__global__ __launch_bounds__(256) void qks2_k(
    const float* __restrict__ x, const float* __restrict__ A,
    const float* __restrict__ S12, float* __restrict__ qsarr,
    float* __restrict__ ksarr) {
  __shared__ __align__(16) float Alds[128 * 36];
  __shared__ float wred[4][8][2][32];
  __shared__ float wred2[4][8][2][2];
  __shared__ float rowstat[16][2];

  const int t = threadIdx.x;
  const int rowp = t & 7, sub = t >> 3;
  const int wid = t >> 6, lane = t & 63;
  const int r0 = blockIdx.x * 16;

  float acc[2][32];
#pragma unroll
  for (int rr = 0; rr < 2; ++rr)
#pragma unroll
    for (int i = 0; i < 32; ++i) acc[rr][i] = 0.f;
  float sx[2] = {0.f, 0.f}, sq[2] = {0.f, 0.f};

  for (int ch = 0; ch < 8; ++ch) {
    __syncthreads();
#pragma unroll
    for (int j = 0; j < 4; ++j) {
      const int f = t + 256 * j;
      const float4 av = *(const float4*)&A[ch * 4096 + f * 4];
      *(float4*)&Alds[(f >> 3) * 36 + (f & 7) * 4] = av;
    }
    __syncthreads();
#pragma unroll
    for (int rr = 0; rr < 2; ++rr) {
      const int row = r0 + rowp * 2 + rr;
      const float4 xv = *(const float4*)&x[(size_t)row * 1024 + ch * 128 + sub * 4];
      const float xs[4] = {xv.x, xv.y, xv.z, xv.w};
#pragma unroll
      for (int kk = 0; kk < 4; ++kk) {
        sx[rr] += xs[kk];
        sq[rr] = fmaf(xs[kk], xs[kk], sq[rr]);
        const float* ap = &Alds[(sub * 4 + kk) * 36];
#pragma unroll
        for (int i = 0; i < 32; ++i)
          acc[rr][i] = fmaf(xs[kk], ap[i], acc[rr][i]);
      }
    }
  }

#pragma unroll
  for (int m = 8; m <= 32; m <<= 1) {
#pragma unroll
    for (int rr = 0; rr < 2; ++rr) {
      sx[rr] += __shfl_xor(sx[rr], m, 64);
      sq[rr] += __shfl_xor(sq[rr], m, 64);
#pragma unroll
      for (int i = 0; i < 32; ++i)
        acc[rr][i] += __shfl_xor(acc[rr][i], m, 64);
    }
  }
  if (lane < 8) {
#pragma unroll
    for (int rr = 0; rr < 2; ++rr) {
#pragma unroll
      for (int i = 0; i < 32; ++i) wred[wid][lane][rr][i] = acc[rr][i];
      wred2[wid][lane][rr][0] = sx[rr];
      wred2[wid][lane][rr][1] = sq[rr];
    }
  }
  __syncthreads();

  if (t < 16) {
    float s = 0.f, q = 0.f;
#pragma unroll
    for (int w = 0; w < 4; ++w) {
      s += wred2[w][t >> 1][t & 1][0];
      q += wred2[w][t >> 1][t & 1][1];
    }
    const float mu = s * (1.f / 1024.f);
    const float var = q * (1.f / 1024.f) - mu * mu;
    rowstat[t][0] = mu;
    rowstat[t][1] = rsqrtf(var + 1e-5f);
  }
  __syncthreads();

#pragma unroll
  for (int o = 0; o < 2; ++o) {
    const int idx = t * 2 + o;
    const int rl = idx >> 5, h = idx & 31;
    const float dot = wred[0][rl >> 1][rl & 1][h] + wred[1][rl >> 1][rl & 1][h] +
                      wred[2][rl >> 1][rl & 1][h] + wred[3][rl >> 1][rl & 1][h];
    const float mu = rowstat[rl][0], rstd = rowstat[rl][1];
    const float val = rstd * (dot - mu * S12[h]) + S12[32 + h];
    const int row = r0 + rl, mm = row >> 3, bb = row & 7;
    if (h < 16)
      qsarr[(size_t)(bb * 16 + h) * 1024 + mm] = val;
    else
      ksarr[(size_t)(bb * 16 + h - 16) * 1024 + mm] = val;
  }
}

// wqsa[k][h32] = sum over the 64 in-head cols of wq (h32<16) / wk (h32>=16)
__global__ void wsum_k(const float* __restrict__ wq,
                       const float* __restrict__ wk,
                       float* __restrict__ wqsa) {
  const int k = blockIdx.x, t = threadIdx.x;
  const int h32 = t >> 3, ch = t & 7;
  const float* src = (h32 < 16) ? (wq + (size_t)k * 1024 + h32 * 64 + ch * 8)
                                : (wk + (size_t)k * 1024 + (h32 - 16) * 64 + ch * 8);
  float s = 0.f;
#pragma unroll
  for (int j = 0; j < 8; ++j) s += src[j];
  s += __shfl_xor(s, 1, 64);
  s += __shfl_xor(s, 2, 64);
  s += __shfl_xor(s, 4, 64);
  if (ch == 0) wqsa[k * 32 + h32] = s;
}

__global__ void bsum_k(const float* __restrict__ bq,
                       const float* __restrict__ bk,
                       float* __restrict__ bqks) {
  const int t = threadIdx.x;
  if (t < 32) {
    const float* s = (t < 16) ? (bq + t * 64) : (bk + (t - 16) * 64);
    float a = 0.f;
    for (int j = 0; j < 64; ++j) a += s[j];
    bqks[t] = a;
  }
}

// A[k][h] = ln1g[k] * wqsa[k][h]
__global__ void afill_k(const float* __restrict__ wqsa,
                        const float* __restrict__ g,
                        float* __restrict__ A) {
  const int f = blockIdx.x * 256 + threadIdx.x;
  const float gv = g[f >> 3];
  const float4 wv = *(const float4*)&wqsa[f * 4];
  float4 av;
  av.x = wv.x * gv; av.y = wv.y * gv; av.z = wv.z * gv; av.w = wv.w * gv;
  *(float4*)&A[f * 4] = av;
}

// S12[h] = sum_k g[k]*wqsa[k][h]; S12[32+h] = sum_k lb[k]*wqsa[k][h] + bqks[h]
__global__ void s12_k(const float* __restrict__ wqsa,
                      const float* __restrict__ g,
                      const float* __restrict__ lb,
                      const float* __restrict__ bqks,
                      float* __restrict__ S12) {
  __shared__ float red1[8][32], red2[8][32];
  const int t = threadIdx.x;
  const int h = t & 31, seg = t >> 5;
  float s1 = 0.f, s2 = 0.f;
  for (int k = seg * 128; k < seg * 128 + 128; ++k) {
    const float a = wqsa[k * 32 + h];
    s1 = fmaf(g[k], a, s1);
    s2 = fmaf(lb[k], a, s2);
  }
  red1[seg][h] = s1;
  red2[seg][h] = s2;
  __syncthreads();
  if (t < 32) {
    float a1 = 0.f, a2 = 0.f;
#pragma unroll
    for (int s = 0; s < 8; ++s) { a1 += red1[s][t]; a2 += red2[s][t]; }
    S12[t] = a1;
    S12[32 + t] = a2 + bqks[t];
  }
}

// W (RxC fp32) -> Wt (CxR bf16)
__global__ void tr_k(const float* __restrict__ W, u16* __restrict__ Wt,
                     int R, int C) {
  __shared__ float tile[32][33];
  const int x = threadIdx.x, y = threadIdx.y;
  const int c0 = blockIdx.x * 32, r0 = blockIdx.y * 32;
#pragma unroll
  for (int i = 0; i < 4; ++i)
    tile[y + i * 8][x] = W[(size_t)(r0 + y + i * 8) * C + c0 + x];
  __syncthreads();
#pragma unroll
  for (int i = 0; i < 4; ++i)
    Wt[(size_t)(c0 + y + i * 8) * R + r0 + x] = f2bf(tile[x][y + i * 8]);
}

extern "C" void kernel_launch(void* const* d_in, const int* in_sizes, int n_in,
                              void* d_out, int out_size, void* d_ws,
                              size_t ws_size, hipStream_t stream) {
  const float* x = (const float*)d_in[0];
  const unsigned char* mask = (const unsigned char*)d_in[1];
  const float* ln1g = (const float*)d_in[2];
  const float* ln1b = (const float*)d_in[3];
  const float* wq = (const float*)d_in[4];
  const float* bq = (const float*)d_in[5];
  const float* wk = (const float*)d_in[6];
  const float* bk = (const float*)d_in[7];
  const float* wv = (const float*)d_in[8];
  const float* bv = (const float*)d_in[9];
  const float* wo = (const float*)d_in[10];
  const float* bo = (const float*)d_in[11];
  const float* ln2g = (const float*)d_in[12];
  const float* ln2b = (const float*)d_in[13];
  const float* w1 = (const float*)d_in[14];
  const float* b1 = (const float*)d_in[15];
  const float* w2 = (const float*)d_in[16];
  const float* b2 = (const float*)d_in[17];

  // ---- workspace layout (~69.3 MB) ----
  u16* wvT = (u16*)d_ws;                        // 1024x1024 bf16
  u16* woT = wvT + 1024 * 1024;                 // 1024x1024
  u16* w1T = woT + 1024 * 1024;                 // 4096x1024
  u16* w2T = w1T + 4096 * 1024;                 // 1024x4096
  float* wqsa = (float*)(w2T + 1024 * 4096);    // [1024][32] f32
  float* bqks = wqsa + 1024 * 32;               // 32 f32
  float* Aq = bqks + 32;                        // [1024][32] f32 (g-folded)
  float* S12 = Aq + 1024 * 32;                  // 64 f32
  float* qsarr = S12 + 64;                      // [8][16][1024] f32
  float* ksarr = qsarr + 8 * 16 * 1024;         // [8][16][1024] f32
  u16* v = (u16*)(ksarr + 8 * 16 * 1024);       // 8192x1024 bf16
  u16* pooled = v + (size_t)8192 * 1024;        // 8192x1024 bf16
  u16* xn = pooled + (size_t)8192 * 1024;       // 8192x1024 bf16
  u16* hbuf = v;                                // alias: 8192x2048 (v+pooled)
  float* x2 = (float*)d_out;                    // fp32 residual in d_out

  const dim3 b256(256), btr(32, 8);
  tr_k<<<dim3(32, 32), btr, 0, stream>>>(wv, wvT, 1024, 1024);
  tr_k<<<dim3(32, 32), btr, 0, stream>>>(wo, woT, 1024, 1024);
  tr_k<<<dim3(128, 32), btr, 0, stream>>>(w1, w1T, 1024, 4096);
  tr_k<<<dim3(32, 128), btr, 0, stream>>>(w2, w2T, 4096, 1024);
  wsum_k<<<dim3(1024), b256, 0, stream>>>(wq, wk, wqsa);
  bsum_k<<<dim3(1), dim3(64), 0, stream>>>(bq, bk, bqks);
  afill_k<<<dim3(32), b256, 0, stream>>>(wqsa, ln1g, Aq);
  s12_k<<<dim3(1), b256, 0, stream>>>(wqsa, ln1g, ln1b, bqks, S12);

  ln_k<<<dim3(8192), b256, 0, stream>>>(x, ln1g, ln1b, xn);
  qks2_k<<<dim3(512), b256, 0, stream>>>(x, Aq, S12, qsarr, ksarr);
  gemm_k<true, false, false, true><<<dim3(8, 64), b256, 0, stream>>>(
      xn, wvT, bv, nullptr, v, 1024, 1024, 1024, 1024);
  attn2_k<<<dim3(16, 128), b256, 0, stream>>>(v, qsarr, ksarr, mask, pooled);
  gemm_k<false, false, true, true><<<dim3(8, 64), b256, 0, stream>>>(
      pooled, woT, bo, x, x2, 1024, 1024, 1024, 1024);
  ln_k<<<dim3(8192), b256, 0, stream>>>(x2, ln2g, ln2b, xn);
  // FF in two K-slices of 2048 so hbuf (8192x2048) fits in v+pooled region
  gemm_k<true, true, false, true><<<dim3(16, 64), b256, 0, stream>>>(
      xn, w1T, b1, nullptr, hbuf, 1024, 2048, 1024, 1024);
  gemm_k<false, false, true, true><<<dim3(8, 64), b256, 0, stream>>>(
      hbuf, w2T, b2, x2, x2, 2048, 1024, 2048, 4096);
  gemm_k<true, true, false, true><<<dim3(16, 64), b256, 0, stream>>>(
      xn, w1T + (size_t)2048 * 1024, b1 + 2048, nullptr, hbuf, 1024, 2048,
      1024, 1024);
  gemm_k<false, false, true, false><<<dim3(8, 64), b256, 0, stream>>>(
      hbuf, w2T + 2048, nullptr, x2, x2, 2048, 1024, 2048, 4096);
}

// Round 8
// 477.071 us; speedup vs baseline: 1.4782x; 1.0583x over previous
//
#include <hip/hip_runtime.h>
#include <hip/hip_bf16.h>

typedef float fv4 __attribute__((ext_vector_type(4)));
typedef __bf16 bfv8 __attribute__((ext_vector_type(8)));
typedef unsigned short u16;

#define DEV static __device__ __forceinline__

DEV u16 f2bf(float f) {
  union { __hip_bfloat16 h; u16 u; } c;
  c.h = __float2bfloat16(f);
  return c.u;
}

DEV void glds16(const void* g, void* l) {
  __builtin_amdgcn_global_load_lds(
      (const __attribute__((address_space(1))) unsigned int*)g,
      (__attribute__((address_space(3))) unsigned int*)l, 16, 0, 0);
}

DEV fv4 mfma16(bfv8 a, bfv8 b, fv4 c) {
  return __builtin_amdgcn_mfma_f32_16x16x32_bf16(a, b, c, 0, 0, 0);
}

// ---------------------------------------------------------------------------
// GEMM: C[MrxN] = A[Mr x K](bf16, row stride lda) @ Bt[N x K](bf16, stride
// ldb)^T + bias (+resid, relu). 128x128 tile, BK=32, 4 waves, 4x4 frags.
// LDS XOR-swizzle (row&7)<<4 via pre-swizzled global_load_lds source.
// XCD-aware block swizzle (bijective; all grids have nwg % 8 == 0).
// ---------------------------------------------------------------------------
template <bool OUT_BF16, bool RELU, bool RESID, bool BIAS>
__global__ __launch_bounds__(256, 2) void gemm_k(
    const u16* __restrict__ A, const u16* __restrict__ Bt,
    const float* __restrict__ bias, const float* __restrict__ resid,
    void* __restrict__ outp, int K, int N, int lda, int ldb) {
  __shared__ __align__(16) u16 lds[2][2][128 * 32];
  const int tid = threadIdx.x;
  const int lane = tid & 63, wid = tid >> 6;
  // XCD swizzle: hardware id -> logical tile so each XCD gets a contiguous
  // chunk of tile space (nwg % 8 == 0 for every launch in this file).
  const int gx = gridDim.x;
  const int nwg = gx * gridDim.y;
  int wg = blockIdx.y * gx + blockIdx.x;
  wg = (wg & 7) * (nwg >> 3) + (wg >> 3);
  const int bm0 = (wg / gx) * 128, bn0 = (wg % gx) * 128;
  const int wr = (wid >> 1) * 64, wc = (wid & 1) * 64;
  const int g = lane >> 4, ml = lane & 15;

  fv4 acc[4][4];
#pragma unroll
  for (int i = 0; i < 4; ++i)
#pragma unroll
    for (int j = 0; j < 4; ++j) acc[i][j] = (fv4)0.f;

  const int nK = K >> 5;

  auto stage = [&](int t) {
    const int buf = t & 1;
    const int k0 = t * 32;
#pragma unroll
    for (int p = 0; p < 2; ++p) {
      const int s = p * 256 + tid;
      const int r0 = ((s >> 2) & 1) ^ ((s >> 4) & 1);
      const int row = ((s >> 3) << 1) | r0;
      const int chunk = (s & 3) ^ (row & 3);
      glds16(A + (size_t)(bm0 + row) * lda + k0 + chunk * 8,
             &lds[buf][0][(p * 256 + wid * 64) * 8]);
      glds16(Bt + (size_t)(bn0 + row) * ldb + k0 + chunk * 8,
             &lds[buf][1][(p * 256 + wid * 64) * 8]);
    }
  };

  stage(0);
  for (int t = 0; t < nK; ++t) {
    __syncthreads();
    if (t + 1 < nK) stage(t + 1);
    const u16* Ab = lds[t & 1][0];
    const u16* Bb = lds[t & 1][1];
    bfv8 af[4], bf[4];
#pragma unroll
    for (int f = 0; f < 4; ++f) {
      const int ra = wr + f * 16 + ml;
      const int ba = ((ra << 6) + (g << 4)) ^ ((ra & 7) << 4);
      af[f] = *(const bfv8*)&Ab[ba >> 1];
      const int rb = wc + f * 16 + ml;
      const int bb = ((rb << 6) + (g << 4)) ^ ((rb & 7) << 4);
      bf[f] = *(const bfv8*)&Bb[bb >> 1];
    }
#pragma unroll
    for (int i = 0; i < 4; ++i)
#pragma unroll
      for (int j = 0; j < 4; ++j) acc[i][j] = mfma16(af[i], bf[j], acc[i][j]);
  }

#pragma unroll
  for (int j = 0; j < 4; ++j) {
    const int n = bn0 + wc + j * 16 + ml;
    float bv = 0.f;
    if (BIAS) bv = bias[n];
#pragma unroll
    for (int i = 0; i < 4; ++i) {
      const int m0r = bm0 + wr + i * 16 + g * 4;
#pragma unroll
      for (int r = 0; r < 4; ++r) {
        float val = acc[i][j][r] + bv;
        if (RESID) val += resid[(size_t)(m0r + r) * N + n];
        if (RELU) val = fmaxf(val, 0.f);
        if (OUT_BF16)
          ((u16*)outp)[(size_t)(m0r + r) * N + n] = f2bf(val);
        else
          ((float*)outp)[(size_t)(m0r + r) * N + n] = val;
      }
    }
  }
}

// ---------------------------------------------------------------------------
// vt_k: V pre-transpose. v[(n*8+b)][h*64+dh] -> vt[(b*16+h)*64+dh][n] with
// chunk-XOR swizzle baked: within each 64-key tile, logical chunk nc lives at
// physical chunk nc ^ (dh&7). Block: one (b,h) x one 64-key tile.
// ---------------------------------------------------------------------------
__global__ __launch_bounds__(256) void vt_k(const u16* __restrict__ v,
                                            u16* __restrict__ vt) {
  __shared__ __align__(16) u16 Tl[64 * 72];
  const int bh = blockIdx.y, b = bh >> 4, h = bh & 15;
  const int nt = blockIdx.x;
  const int t = threadIdx.x;

  // load 64 keys x 64 dh (coalesced 128B per key row)
#pragma unroll
  for (int p = 0; p < 2; ++p) {
    const int cidx = p * 256 + t;
    const int j = cidx >> 3, c = cidx & 7;
    bfv8 val = *(const bfv8*)&v[((size_t)(nt * 64 + j) * 8 + b) * 1024 +
                                h * 64 + c * 8];
    *(bfv8*)&Tl[j * 72 + c * 8] = val;
  }
  __syncthreads();

  // write transposed: out chunk (dh, nc) gathers Tl[nc*8+jj][dh]
#pragma unroll
  for (int p = 0; p < 2; ++p) {
    const int cidx = p * 256 + t;
    const int dh = cidx >> 3, nc = cidx & 7;
    u16 tmp[8];
#pragma unroll
    for (int jj = 0; jj < 8; ++jj) tmp[jj] = Tl[(nc * 8 + jj) * 72 + dh];
    *(bfv8*)&vt[((size_t)(bh * 64 + dh)) * 1024 + nt * 64 +
                (nc ^ (dh & 7)) * 8] = *(const bfv8*)tmp;
  }
}

// ---------------------------------------------------------------------------
// attn3: rank-1-logit attention, 4 m-tiles per block.
// Block = (b,h) x 256 m-rows; wave owns 64 rows (4 frags of 16).
// V staged via glds16 from pre-swizzled vt (zero scalar LDS writes),
// double-buffered; VT reads hoisted across the 4 m-frags.
// ---------------------------------------------------------------------------
__global__ __launch_bounds__(256, 2) void attn3_k(
    const u16* __restrict__ vt, const float* __restrict__ qsarr,
    const float* __restrict__ ksarr, const unsigned char* __restrict__ mask,
    u16* __restrict__ pooled) {
  __shared__ float ks_s[1024];
  __shared__ float red[16];
  __shared__ int anym_s;
  __shared__ float zl[4][4][16];
  __shared__ __align__(16) u16 VT[2][64 * 64];
  __shared__ __align__(16) u16 stg[4][16 * 72];

  const int tid = threadIdx.x, lane = tid & 63, wid = tid >> 6;
  const int g = lane >> 4, ml = lane & 15;
  const int bh = blockIdx.y, b = bh >> 4, h = bh & 15;
  const int mbase = blockIdx.x * 256 + wid * 64;

  if (tid == 0) anym_s = 0;
  __syncthreads();

  // stage ks (fp32) + unmasked max/min + any-mask flag
  const float* ksp = ksarr + (size_t)bh * 1024;
  float4 kv = *(const float4*)&ksp[tid * 4];
  *(float4*)&ks_s[tid * 4] = kv;
  const float kvv[4] = {kv.x, kv.y, kv.z, kv.w};
  float mx = -3.4e38f, mn = 3.4e38f;
  int am = 0;
#pragma unroll
  for (int j = 0; j < 4; ++j) {
    const int n = tid * 4 + j;
    const int mk = mask[(size_t)n * 8 + b] ? 1 : 0;
    am |= mk;
    if (!mk) { mx = fmaxf(mx, kvv[j]); mn = fminf(mn, kvv[j]); }
  }
  if (am) atomicOr(&anym_s, 1);
#pragma unroll
  for (int s = 1; s <= 32; s <<= 1) {
    mx = fmaxf(mx, __shfl_xor(mx, s, 64));
    mn = fminf(mn, __shfl_xor(mn, s, 64));
  }
  if (lane == 0) { red[wid] = mx; red[8 + wid] = mn; }
  __syncthreads();
  const float smax = fmaxf(fmaxf(red[0], red[1]), fmaxf(red[2], red[3]));
  const float smin = fminf(fminf(red[8], red[9]), fminf(red[10], red[11]));
  const int anym = anym_s;

  float c[4], M[4];
#pragma unroll
  for (int mf = 0; mf < 4; ++mf) {
    c[mf] = qsarr[(size_t)bh * 1024 + mbase + mf * 16 + ml];
    M[mf] = (c[mf] >= 0.f) ? c[mf] * smax : c[mf] * smin;  // M >= 0 always
  }

  fv4 o[4][4];
#pragma unroll
  for (int mf = 0; mf < 4; ++mf)
#pragma unroll
    for (int d = 0; d < 4; ++d) o[mf][d] = (fv4)0.f;
  float zacc[4] = {0.f, 0.f, 0.f, 0.f};

  const size_t vtbase = (size_t)bh * 64 * 1024;
  auto stageV = [&](int nt) {
    const int buf = nt & 1;
#pragma unroll
    for (int p = 0; p < 2; ++p) {
      const int s = p * 256 + tid;
      glds16(&vt[vtbase + (size_t)(s >> 3) * 1024 + nt * 64 + (s & 7) * 8],
             &VT[buf][s * 8]);
    }
  };

  stageV(0);
  for (int nt = 0; nt < 16; ++nt) {
    __syncthreads();
    if (nt + 1 < 16) stageV(nt + 1);
    const u16* Vb = VT[nt & 1];
    const int n0 = nt * 64;
#pragma unroll
    for (int kk = 0; kk < 2; ++kk) {
      const int kb = n0 + kk * 32 + g * 8;
      const float4 s0 = *(const float4*)&ks_s[kb];
      const float4 s1 = *(const float4*)&ks_s[kb + 4];
      const float sv[8] = {s0.x, s0.y, s0.z, s0.w, s1.x, s1.y, s1.z, s1.w};
      int mk[8] = {0, 0, 0, 0, 0, 0, 0, 0};
      if (anym) {
#pragma unroll
        for (int j = 0; j < 8; ++j) mk[j] = mask[(size_t)(kb + j) * 8 + b];
      }
      bfv8 pa[4];
#pragma unroll
      for (int mf = 0; mf < 4; ++mf) {
        u16 tmp[8];
#pragma unroll
        for (int j = 0; j < 8; ++j) {
          float p = __expf(fmaf(c[mf], sv[j], -M[mf]));
          if (anym && mk[j]) p = 0.f;
          zacc[mf] += p;
          tmp[j] = f2bf(p);
        }
        pa[mf] = *(const bfv8*)tmp;
      }
#pragma unroll
      for (int ds = 0; ds < 4; ++ds) {
        const int d = ds * 16 + ml;
        const int pc = (kk * 4 + g) ^ (d & 7);
        bfv8 vf = *(const bfv8*)&Vb[d * 64 + pc * 8];
#pragma unroll
        for (int mf = 0; mf < 4; ++mf)
          o[mf][ds] = mfma16(pa[mf], vf, o[mf][ds]);
      }
    }
  }

  // Z per row: sum partials across the 4 g-groups
#pragma unroll
  for (int mf = 0; mf < 4; ++mf) {
    zacc[mf] += __shfl_xor(zacc[mf], 16, 64);
    zacc[mf] += __shfl_xor(zacc[mf], 32, 64);
  }
  if (g == 0) {
#pragma unroll
    for (int mf = 0; mf < 4; ++mf) zl[wid][mf][ml] = zacc[mf];
  }
  asm volatile("" ::: "memory");  // same-wave LDS write -> read

#pragma unroll
  for (int mf = 0; mf < 4; ++mf) {
    float zin[4];
#pragma unroll
    for (int r = 0; r < 4; ++r) zin[r] = 1.f / zl[wid][mf][g * 4 + r];
#pragma unroll
    for (int ds = 0; ds < 4; ++ds)
#pragma unroll
      for (int r = 0; r < 4; ++r)
        stg[wid][(g * 4 + r) * 72 + ds * 16 + ml] =
            f2bf(o[mf][ds][r] * zin[r]);
    asm volatile("" ::: "memory");
#pragma unroll
    for (int p = 0; p < 2; ++p) {
      const int ch = p * 64 + lane;
      const int mr = ch >> 3, cc = ch & 7;
      bfv8 val = *(const bfv8*)&stg[wid][mr * 72 + cc * 8];
      *(bfv8*)&pooled[((size_t)(mbase + mf * 16 + mr) * 8 + b) * 1024 +
                      h * 64 + cc * 8] = val;
    }
    asm volatile("" ::: "memory");  // stg reused next mf
  }
}

// ---------------------------------------------------------------------------
// LayerNorm: one block per row of 1024, fp32 in -> bf16 out
// ---------------------------------------------------------------------------
__global__ __launch_bounds__(256) void ln_k(
    const float* __restrict__ x, const float* __restrict__ gw,
    const float* __restrict__ bw, u16* __restrict__ out) {
  __shared__ float sm[8];
  const int row = blockIdx.x, tid = threadIdx.x;
  const int lane = tid & 63, wid = tid >> 6;
  const float4 xv = *(const float4*)&x[(size_t)row * 1024 + tid * 4];
  float s = xv.x + xv.y + xv.z + xv.w;
  float q = xv.x * xv.x + xv.y * xv.y + xv.z * xv.z + xv.w * xv.w;
#pragma unroll
  for (int m = 1; m <= 32; m <<= 1) {
    s += __shfl_xor(s, m, 64);
    q += __shfl_xor(q, m, 64);
  }
  if (lane == 0) { sm[wid] = s; sm[4 + wid] = q; }
  __syncthreads();
  s = sm[0] + sm[1] + sm[2] + sm[3];
  q = sm[4] + sm[5] + sm[6] + sm[7];
  const float mean = s * (1.f / 1024.f);
  const float var = q * (1.f / 1024.f) - mean * mean;
  const float rstd = rsqrtf(var + 1e-5f);
  const float4 gv = *(const float4*)&gw[tid * 4];
  const float4 bv = *(const float4*)&bw[tid * 4];
  ushort4 ov;
  ov.x = f2bf((xv.x - mean) * rstd * gv.x + bv.x);
  ov.y = f2bf((xv.y - mean) * rstd * gv.y + bv.y);
  ov.z = f2bf((xv.z - mean) * rstd * gv.z + bv.z);
  ov.w = f2bf((xv.w - mean) * rstd * gv.w + bv.w);
  *(ushort4*)&out[(size_t)row * 1024 + tid * 4] = ov;
}

// ---------------------------------------------------------------------------
// qks2: C[16 rows][32] = X[16x1024] @ A[1024x32] with LN folded into A:
// qs_h = rstd*(dot_h - mu*S1_h) + S2_h. Block: 256 threads, 16 rows.
// ---------------------------------------------------------------------------
__global__ __launch_bounds__(256) void qks2_k(
    const float* __restrict__ x, const float* __restrict__ A,
    const float* __restrict__ S12, float* __restrict__ qsarr,
    float* __restrict__ ksarr) {
  __shared__ __align__(16) float Alds[128 * 36];
  __shared__ float wred[4][8][2][32];
  __shared__ float wred2[4][8][2][2];
  __shared__ float rowstat[16][2];

  const int t = threadIdx.x;
  const int rowp = t & 7, sub = t >> 3;
  const int wid = t >> 6, lane = t & 63;
  const int r0 = blockIdx.x * 16;

  float acc[2][32];
#pragma unroll
  for (int rr = 0; rr < 2; ++rr)
#pragma unroll
    for (int i = 0; i < 32; ++i) acc[rr][i] = 0.f;
  float sx[2] = {0.f, 0.f}, sq[2] = {0.f, 0.f};

  for (int ch = 0; ch < 8; ++ch) {
    __syncthreads();
#pragma unroll
    for (int j = 0; j < 4; ++j) {
      const int f = t + 256 * j;
      const float4 av = *(const float4*)&A[ch * 4096 + f * 4];
      *(float4*)&Alds[(f >> 3) * 36 + (f & 7) * 4] = av;
    }
    __syncthreads();
#pragma unroll
    for (int rr = 0; rr < 2; ++rr) {
      const int row = r0 + rowp * 2 + rr;
      const float4 xv = *(const float4*)&x[(size_t)row * 1024 + ch * 128 + sub * 4];
      const float xs[4] = {xv.x, xv.y, xv.z, xv.w};
#pragma unroll
      for (int kk = 0; kk < 4; ++kk) {
        sx[rr] += xs[kk];
        sq[rr] = fmaf(xs[kk], xs[kk], sq[rr]);
        const float* ap = &Alds[(sub * 4 + kk) * 36];
#pragma unroll
        for (int i = 0; i < 32; ++i)
          acc[rr][i] = fmaf(xs[kk], ap[i], acc[rr][i]);
      }
    }
  }

#pragma unroll
  for (int m = 8; m <= 32; m <<= 1) {
#pragma unroll
    for (int rr = 0; rr < 2; ++rr) {
      sx[rr] += __shfl_xor(sx[rr], m, 64);
      sq[rr] += __shfl_xor(sq[rr], m, 64);
#pragma unroll
      for (int i = 0; i < 32; ++i)
        acc[rr][i] += __shfl_xor(acc[rr][i], m, 64);
    }
  }
  if (lane < 8) {
#pragma unroll
    for (int rr = 0; rr < 2; ++rr) {
#pragma unroll
      for (int i = 0; i < 32; ++i) wred[wid][lane][rr][i] = acc[rr][i];
      wred2[wid][lane][rr][0] = sx[rr];
      wred2[wid][lane][rr][1] = sq[rr];
    }
  }
  __syncthreads();

  if (t < 16) {
    float s = 0.f, q = 0.f;
#pragma unroll
    for (int w = 0; w < 4; ++w) {
      s += wred2[w][t >> 1][t & 1][0];
      q += wred2[w][t >> 1][t & 1][1];
    }
    const float mu = s * (1.f / 1024.f);
    const float var = q * (1.f / 1024.f) - mu * mu;
    rowstat[t][0] = mu;
    rowstat[t][1] = rsqrtf(var + 1e-5f);
  }
  __syncthreads();

#pragma unroll
  for (int o = 0; o < 2; ++o) {
    const int idx = t * 2 + o;
    const int rl = idx >> 5, h = idx & 31;
    const float dot = wred[0][rl >> 1][rl & 1][h] + wred[1][rl >> 1][rl & 1][h] +
                      wred[2][rl >> 1][rl & 1][h] + wred[3][rl >> 1][rl & 1][h];
    const float mu = rowstat[rl][0], rstd = rowstat[rl][1];
    const float val = rstd * (dot - mu * S12[h]) + S12[32 + h];
    const int row = r0 + rl, mm = row >> 3, bb = row & 7;
    if (h < 16)
      qsarr[(size_t)(bb * 16 + h) * 1024 + mm] = val;
    else
      ksarr[(size_t)(bb * 16 + h - 16) * 1024 + mm] = val;
  }
}

// wqsa[k][h32] = sum over the 64 in-head cols of wq (h32<16) / wk (h32>=16)
__global__ void wsum_k(const float* __restrict__ wq,
                       const float* __restrict__ wk,
                       float* __restrict__ wqsa) {
  const int k = blockIdx.x, t = threadIdx.x;
  const int h32 = t >> 3, ch = t & 7;
  const float* src = (h32 < 16) ? (wq + (size_t)k * 1024 + h32 * 64 + ch * 8)
                                : (wk + (size_t)k * 1024 + (h32 - 16) * 64 + ch * 8);
  float s = 0.f;
#pragma unroll
  for (int j = 0; j < 8; ++j) s += src[j];
  s += __shfl_xor(s, 1, 64);
  s += __shfl_xor(s, 2, 64);
  s += __shfl_xor(s, 4, 64);
  if (ch == 0) wqsa[k * 32 + h32] = s;
}

__global__ void bsum_k(const float* __restrict__ bq,
                       const float* __restrict__ bk,
                       float* __restrict__ bqks) {
  const int t = threadIdx.x;
  if (t < 32) {
    const float* s = (t < 16) ? (bq + t * 64) : (bk + (t - 16) * 64);
    float a = 0.f;
    for (int j = 0; j < 64; ++j) a += s[j];
    bqks[t] = a;
  }
}

// A[k][h] = ln1g[k] * wqsa[k][h]
__global__ void afill_k(const float* __restrict__ wqsa,
                        const float* __restrict__ g,
                        float* __restrict__ A) {
  const int f = blockIdx.x * 256 + threadIdx.x;
  const float gv = g[f >> 3];
  const float4 wv = *(const float4*)&wqsa[f * 4];
  float4 av;
  av.x = wv.x * gv; av.y = wv.y * gv; av.z = wv.z * gv; av.w = wv.w * gv;
  *(float4*)&A[f * 4] = av;
}

// S12[h] = sum_k g[k]*wqsa[k][h]; S12[32+h] = sum_k lb[k]*wqsa[k][h] + bqks[h]
__global__ void s12_k(const float* __restrict__ wqsa,
                      const float* __restrict__ g,
                      const float* __restrict__ lb,
                      const float* __restrict__ bqks,
                      float* __restrict__ S12) {
  __shared__ float red1[8][32], red2[8][32];
  const int t = threadIdx.x;
  const int h = t & 31, seg = t >> 5;
  float s1 = 0.f, s2 = 0.f;
  for (int k = seg * 128; k < seg * 128 + 128; ++k) {
    const float a = wqsa[k * 32 + h];
    s1 = fmaf(g[k], a, s1);
    s2 = fmaf(lb[k], a, s2);
  }
  red1[seg][h] = s1;
  red2[seg][h] = s2;
  __syncthreads();
  if (t < 32) {
    float a1 = 0.f, a2 = 0.f;
#pragma unroll
    for (int s = 0; s < 8; ++s) { a1 += red1[s][t]; a2 += red2[s][t]; }
    S12[t] = a1;
    S12[32 + t] = a2 + bqks[t];
  }
}

// W (RxC fp32) -> Wt (CxR bf16)
__global__ void tr_k(const float* __restrict__ W, u16* __restrict__ Wt,
                     int R, int C) {
  __shared__ float tile[32][33];
  const int x = threadIdx.x, y = threadIdx.y;
  const int c0 = blockIdx.x * 32, r0 = blockIdx.y * 32;
#pragma unroll
  for (int i = 0; i < 4; ++i)
    tile[y + i * 8][x] = W[(size_t)(r0 + y + i * 8) * C + c0 + x];
  __syncthreads();
#pragma unroll
  for (int i = 0; i < 4; ++i)
    Wt[(size_t)(c0 + y + i * 8) * R + r0 + x] = f2bf(tile[x][y + i * 8]);
}

extern "C" void kernel_launch(void* const* d_in, const int* in_sizes, int n_in,
                              void* d_out, int out_size, void* d_ws,
                              size_t ws_size, hipStream_t stream) {
  const float* x = (const float*)d_in[0];
  const unsigned char* mask = (const unsigned char*)d_in[1];
  const float* ln1g = (const float*)d_in[2];
  const float* ln1b = (const float*)d_in[3];
  const float* wq = (const float*)d_in[4];
  const float* bq = (const float*)d_in[5];
  const float* wk = (const float*)d_in[6];
  const float* bk = (const float*)d_in[7];
  const float* wv = (const float*)d_in[8];
  const float* bv = (const float*)d_in[9];
  const float* wo = (const float*)d_in[10];
  const float* bo = (const float*)d_in[11];
  const float* ln2g = (const float*)d_in[12];
  const float* ln2b = (const float*)d_in[13];
  const float* w1 = (const float*)d_in[14];
  const float* b1 = (const float*)d_in[15];
  const float* w2 = (const float*)d_in[16];
  const float* b2 = (const float*)d_in[17];

  // ---- workspace layout (~85.3 MB) ----
  u16* wvT = (u16*)d_ws;                        // 1024x1024 bf16
  u16* woT = wvT + 1024 * 1024;                 // 1024x1024
  u16* w1T = woT + 1024 * 1024;                 // 4096x1024
  u16* w2T = w1T + 4096 * 1024;                 // 1024x4096
  float* wqsa = (float*)(w2T + 1024 * 4096);    // [1024][32] f32
  float* bqks = wqsa + 1024 * 32;               // 32 f32
  float* Aq = bqks + 32;                        // [1024][32] f32 (g-folded)
  float* S12 = Aq + 1024 * 32;                  // 64 f32
  float* qsarr = S12 + 64;                      // [8][16][1024] f32
  float* ksarr = qsarr + 8 * 16 * 1024;         // [8][16][1024] f32
  u16* v = (u16*)(ksarr + 8 * 16 * 1024);       // 8192x1024 bf16
  u16* pooled = v + (size_t)8192 * 1024;        // 8192x1024 bf16
  u16* xn = pooled + (size_t)8192 * 1024;       // 8192x1024 bf16
  u16* vtb = xn + (size_t)8192 * 1024;          // 8192x1024 bf16 (V^T swz)
  u16* hbuf = v;                                // alias: 8192x2048 (v+pooled)
  float* x2 = (float*)d_out;                    // fp32 residual in d_out

  const dim3 b256(256), btr(32, 8);
  tr_k<<<dim3(32, 32), btr, 0, stream>>>(wv, wvT, 1024, 1024);
  tr_k<<<dim3(32, 32), btr, 0, stream>>>(wo, woT, 1024, 1024);
  tr_k<<<dim3(128, 32), btr, 0, stream>>>(w1, w1T, 1024, 4096);
  tr_k<<<dim3(32, 128), btr, 0, stream>>>(w2, w2T, 4096, 1024);
  wsum_k<<<dim3(1024), b256, 0, stream>>>(wq, wk, wqsa);
  bsum_k<<<dim3(1), dim3(64), 0, stream>>>(bq, bk, bqks);
  afill_k<<<dim3(32), b256, 0, stream>>>(wqsa, ln1g, Aq);
  s12_k<<<dim3(1), b256, 0, stream>>>(wqsa, ln1g, ln1b, bqks, S12);

  ln_k<<<dim3(8192), b256, 0, stream>>>(x, ln1g, ln1b, xn);
  qks2_k<<<dim3(512), b256, 0, stream>>>(x, Aq, S12, qsarr, ksarr);
  gemm_k<true, false, false, true><<<dim3(8, 64), b256, 0, stream>>>(
      xn, wvT, bv, nullptr, v, 1024, 1024, 1024, 1024);
  vt_k<<<dim3(16, 128), b256, 0, stream>>>(v, vtb);
  attn3_k<<<dim3(4, 128), b256, 0, stream>>>(vtb, qsarr, ksarr, mask, pooled);
  gemm_k<false, false, true, true><<<dim3(8, 64), b256, 0, stream>>>(
      pooled, woT, bo, x, x2, 1024, 1024, 1024, 1024);
  ln_k<<<dim3(8192), b256, 0, stream>>>(x2, ln2g, ln2b, xn);
  // FF in two K-slices of 2048 so hbuf (8192x2048) fits in v+pooled region
  gemm_k<true, true, false, true><<<dim3(16, 64), b256, 0, stream>>>(
      xn, w1T, b1, nullptr, hbuf, 1024, 2048, 1024, 1024);
  gemm_k<false, false, true, true><<<dim3(8, 64), b256, 0, stream>>>(
      hbuf, w2T, b2, x2, x2, 2048, 1024, 2048, 4096);
  gemm_k<true, true, false, true><<<dim3(16, 64), b256, 0, stream>>>(
      xn, w1T + (size_t)2048 * 1024, b1 + 2048, nullptr, hbuf, 1024, 2048,
      1024, 1024);
  gemm_k<false, false, true, false><<<dim3(8, 64), b256, 0, stream>>>(
      hbuf, w2T + 2048, nullptr, x2, x2, 2048, 1024, 2048, 4096);
}